// Round 2
// baseline (99115.369 us; speedup 1.0000x reference)
//
#include <hip/hip_runtime.h>

// ============================================================================
// CustomMultiInputLSTM (B=64, H=512, T=1024, 7 aux) on gfx950 — round 7.
//
// Round 5 (36.5ms): WG-gated dataflow, 208 WGs, 32-col tiles.
// Round 6 (52.8ms, REGRESSION): per-wave scattered polling multiplied LLC
// contention. Counters: 40 GB sc1 traffic @ 757 GB/s == the whole runtime.
// Traffic = replication: h read by 144 WGs (19GB), l by 64 WGs x 16 col
// slices (17GB).
//
// Round 7: halve the replication factor.
//   A: 9 ch x 8 col-slices (64 cols) = 72 WGs  -> h traffic 19 -> 9.6 GB
//   B: 4 row x 8 col-slices (64 cols) = 32 WGs -> l traffic 17 -> 8.6 GB
// LDS can't hold hi+lo weights at 64 cols: hi-half in LDS (128KB), lo-half
// read per-step from L2 (static, plain cached loads, WG-private lines).
// kh-reduction via 2-round 16KB LDS exchange. WG-level gate (round-5 style)
// on u16-packed flags (A gate = 1 line, B gate = 3 lines), one polling wave,
// s_sleep(4). fo prefetched at gate. setprio(1) around MFMA.
// All cross-WG data via agent-scope relaxed atomics (sc1, LLC-coherent).
// h/l packed as (f16hi | f16lo<<16) u32; split-f16, 3 MFMAs per frag pair.
// ============================================================================

typedef _Float16 f16;
typedef _Float16 f16x8 __attribute__((ext_vector_type(8)));
typedef float    f32x4 __attribute__((ext_vector_type(4)));
typedef unsigned int       u32;
typedef unsigned long long u64;
typedef unsigned short     u16;

#define DI static __device__ __forceinline__

constexpr int B_   = 64;
constexpr int H_   = 512;
constexpr int T_   = 1024;
constexpr int NTHR = 512;
constexpr int NA_WG = 72;            // 9 channels x 8 col-slices (64 cols)
constexpr int NB_WG = 32;            // 4 row-tiles x 8 col-slices (64 cols)
constexpr int NWG  = NA_WG + NB_WG;  // 104

constexpr size_t MAT_ELE = (size_t)16 * 32 * 64 * 8;   // f16 elems per matrix blob

// ---- LDS pool offsets (role-dependent) -------------------------------------
constexpr int OFF_W    = 0;        // A: 128 frags x 1KB (hi only); B: 64 frags
constexpr int OFF_SMX  = 65536;    // B: l-tile for softmax [8][16][64] u32 32KB
constexpr int OFF_UF   = 98304;    // B: u [8][16][64] f32 32KB
constexpr int OFF_RED  = 131072;   // both: 4 slots x 4KB (2-round exchange)
constexpr int OFF_SINI = 147456;   // A: [64][8] f32 2KB
constexpr int OFF_SINC = 149504;   // A: [64][8] f32 2KB
constexpr int OFF_SWI  = 151552;   // A: [8][64] f32 2KB
constexpr int OFF_SWC  = 153600;   // A: [8][64] f32 2KB
constexpr int OFF_SBI  = 155648;   // A: 64 f32
constexpr int OFF_SBC  = 155904;   // A: 64 f32
constexpr int OFF_CLDS = 147456;   // B: c [16][64] f32 4KB (aliases SINI/SINC)
constexpr int OFF_SBA  = 151552;   // B: b_a slice 256B (aliases SWI)
constexpr int POOL_SZ  = 156160;   // <= 160KB

// ---- static device scratch -------------------------------------------------
__device__ __align__(64) u16 g_hflag[32];
__device__ __align__(64) u16 g_lflag[72];
__device__ __align__(16) u32 g_hp[2][B_ * H_];     // packed h, parity buffers
__device__ __align__(16) u32 g_lp[2][8 * B_ * H_]; // packed l
__device__ __align__(16) u64 g_fo[2][B_ * H_];     // (f32 f | f32 o << 32)
__device__ f16 g_blob1[19 * MAT_ELE];   // weight hi frags
__device__ f16 g_blob2[19 * MAT_ELE];   // weight lo frags (x2048)

struct P {
  const float* Y;
  const float* x[7];
  const float *W_i, *U_i, *b_i, *W_f, *U_f, *b_f;
  const float *W_c, *U_c, *b_c, *W_o, *U_o, *b_o;
  const float *W_i_x, *U_i_x, *b_i_x, *W_c_x, *U_c_x, *b_c_x;
  const float *W_a, *b_a;
  float* out;   // [64*512] h_T, then [64,1024,512] hidden_seq
};

DI f32x4 mfma16(f16x8 a, f16x8 b, f32x4 c) {
  return __builtin_amdgcn_mfma_f32_16x16x32_f16(a, b, c, 0, 0, 0);
}
DI float sigmoidf_(float x) { return 1.0f / (1.0f + expf(-x)); }

// agent-scope relaxed (sc1): bypass per-XCD L2, coherent at LLC
DI u32 lda32(const u32* p) {
  return __hip_atomic_load(p, __ATOMIC_RELAXED, __HIP_MEMORY_SCOPE_AGENT);
}
DI void sta32(u32* p, u32 v) {
  __hip_atomic_store(p, v, __ATOMIC_RELAXED, __HIP_MEMORY_SCOPE_AGENT);
}
DI u64 lda64(const void* p) {
  return __hip_atomic_load((const u64*)p, __ATOMIC_RELAXED, __HIP_MEMORY_SCOPE_AGENT);
}
DI void sta64(void* p, u64 v) {
  __hip_atomic_store((u64*)p, v, __ATOMIC_RELAXED, __HIP_MEMORY_SCOPE_AGENT);
}
DI void sta16(u16* p, u16 v) {
  __hip_atomic_store(p, v, __ATOMIC_RELAXED, __HIP_MEMORY_SCOPE_AGENT);
}
DI u16 f16bits(f16 h) { return __builtin_bit_cast(u16, h); }
DI f16  bitsf16(u16 b) { return __builtin_bit_cast(f16, b); }

// lo-weight fragment load (plain cached — static data, L2-resident)
DI f16x8 ldw(const f16* base, int kt, int nt, int lane) {
  return *(const f16x8*)(base + (((size_t)(kt * 32 + nt) * 64 + lane) * 8));
}

// ---------------------------------------------------------------------------
// Prep: zero flags + h parity buffers; swizzle 19 [512x512] fp32 matrices
// into split-f16 MFMA B-fragment blobs.
// mat ids: 0=U_i, 1..7=U_i_x[k], 8=U_f, 9=U_c, 10..16=U_c_x[k], 17=U_o, 18=W_a
// ---------------------------------------------------------------------------
__global__ void __launch_bounds__(256) prep_kernel(P p) {
  const int gid = blockIdx.x * blockDim.x + threadIdx.x;
  const int nth = gridDim.x * blockDim.x;
  if (gid < 32) g_hflag[gid] = 0;
  if (gid < 72) g_lflag[gid] = 0;
  for (int i = gid; i < 2 * B_ * H_; i += nth) ((u32*)g_hp)[i] = 0u;

  const int lane = threadIdx.x & 63;
  const int wvg  = gid >> 6;
  const int nwv  = nth >> 6;
  for (int tile = wvg; tile < 19 * 16 * 32; tile += nwv) {
    const int mat = tile / (16 * 32);
    const int rem = tile % (16 * 32);
    const int kt = rem >> 5, nt = rem & 31;
    const float* src;
    if      (mat == 0)  src = p.U_i;
    else if (mat <  8)  src = p.U_i_x + (size_t)(mat - 1) * H_ * H_;
    else if (mat == 8)  src = p.U_f;
    else if (mat == 9)  src = p.U_c;
    else if (mat < 17)  src = p.U_c_x + (size_t)(mat - 10) * H_ * H_;
    else if (mat == 17) src = p.U_o;
    else                src = p.W_a;
    const int k0 = kt * 32 + (lane >> 4) * 8;     // B frag: k = quad*8+j
    const int n  = nt * 16 + (lane & 15);         //         n = lane&15
    f16x8 hv, lv;
#pragma unroll
    for (int j = 0; j < 8; ++j) {
      float v  = src[(size_t)(k0 + j) * H_ + n];
      f16   hh = (f16)v;
      hv[j] = hh;
      lv[j] = (f16)((v - (float)hh) * 2048.0f);
    }
    size_t off = (size_t)mat * MAT_ELE + ((size_t)(kt * 32 + nt) * 64 + lane) * 8;
    *(f16x8*)(g_blob1 + off) = hv;
    *(f16x8*)(g_blob2 + off) = lv;
  }
}

// ---------------------------------------------------------------------------
// Main persistent kernel: 104 WGs x 512 threads (8 waves).
//   A-WG (0..71): channel kap = wg>>3, cols C0A = (wg&7)*64.
//     wave = (mh2 = wv>>1: 16-row group, kh = wv&1: K half).
//     Each wave computes BOTH matrices (i-type mat0, c-type mat1), 4 col-frags.
//   B-WG (72..103): (R0B = (w2>>3)*16, C0B = (w2&7)*64).
//     wave = (chPair = wv>>1, kh = wv&1), 4 col-frags.
// ---------------------------------------------------------------------------
__global__ void __launch_bounds__(NTHR, 2) lstm_main(P p) {
  const int wg   = blockIdx.x;
  const int tid  = threadIdx.x;
  const int lane = tid & 63;
  const int wv   = tid >> 6;
  const int quad = lane >> 4;
  const int l15  = lane & 15;

  __shared__ __align__(16) char pool[POOL_SZ];
  float* sInI = (float*)(pool + OFF_SINI);
  float* sInC = (float*)(pool + OFF_SINC);
  float* sWI  = (float*)(pool + OFF_SWI);
  float* sWC  = (float*)(pool + OFF_SWC);
  float* sbI  = (float*)(pool + OFF_SBI);
  float* sbC  = (float*)(pool + OFF_SBC);
  float* sba  = (float*)(pool + OFF_SBA);
  float* cl_  = (float*)(pool + OFF_CLDS);
  float* redf = (float*)(pool + OFF_RED);
  float* uf   = (float*)(pool + OFF_UF);

  const bool isA = (wg < NA_WG);

  int kap = 0, C0A = 0, KI = 8, nt0 = 0;
  const float* inI = p.Y;
  const float* inC = p.Y;
  const f16* loI = g_blob2;
  const f16* loC = g_blob2;
  int R0B = 0, C0B = 0, ktp = 0;

  if (isA) {
    kap = wg >> 3;
    C0A = (wg & 7) * 64;
    nt0 = C0A >> 4;
    KI  = (kap == 0 || kap == 8) ? 8 : 3;
    int matI, matC;
    const float *WIs, *bIs, *WCs, *bCs;
    if (kap == 0)      { WIs = p.W_i; bIs = p.b_i; WCs = p.W_c; bCs = p.b_c; matI = 0; matC = 9; }
    else if (kap == 8) { WIs = p.W_f; bIs = p.b_f; WCs = p.W_o; bCs = p.b_o; matI = 8; matC = 17; }
    else {
      WIs = p.W_i_x + (size_t)(kap - 1) * 3 * H_;
      bIs = p.b_i_x + (size_t)(kap - 1) * H_;
      WCs = p.W_c_x + (size_t)(kap - 1) * 3 * H_;
      bCs = p.b_c_x + (size_t)(kap - 1) * H_;
      inI = (kap == 1) ? p.x[0] : p.x[1];   // xi = [x1, x2, x2, x2, x2, x2, x2]
      inC = p.x[kap - 1];                   // xc = [x1 .. x7]
      matI = kap; matC = 9 + kap;
    }
    loI = g_blob2 + (size_t)matI * MAT_ELE;
    loC = g_blob2 + (size_t)matC * MAT_ELE;
    for (int idx = tid; idx < KI * 64; idx += NTHR) {
      int i = idx >> 6, c = idx & 63;
      sWI[i * 64 + c] = WIs[(size_t)i * H_ + C0A + c];
      sWC[i * 64 + c] = WCs[(size_t)i * H_ + C0A + c];
    }
    if (tid < 64) { sbI[tid] = bIs[C0A + tid]; sbC[tid] = bCs[C0A + tid]; }
    // stage hi weight frags for both matrices: 128 frags x 1KB
    for (int c = tid; c < 8192; c += NTHR) {
      int f = c >> 6, ln = c & 63;
      int ms = f >> 6, kt = (f >> 2) & 15, nn = f & 3;
      int mat = ms ? matC : matI;
      size_t so = (size_t)mat * MAT_ELE + ((size_t)(kt * 32 + nt0 + nn) * 64 + ln) * 8;
      *(f16x8*)(pool + OFF_W + (size_t)f * 1024 + ln * 16) = *(const f16x8*)(g_blob1 + so);
    }
  } else {
    int w2 = wg - NA_WG;
    R0B = (w2 >> 3) * 16;
    C0B = (w2 & 7) * 64;
    nt0 = C0B >> 4;
    ktp = C0B >> 5;                       // softmax l-tile kt pair {ktp, ktp+1}
    if (tid < 64) sba[tid] = p.b_a[C0B + tid];
    for (int idx = tid; idx < 1024; idx += NTHR) cl_[idx] = 0.0f;
    // W_a hi slice: 64 frags x 1KB
    for (int c = tid; c < 4096; c += NTHR) {
      int f = c >> 6, ln = c & 63;
      int kt = f >> 2, nn = f & 3;
      size_t so = (size_t)18 * MAT_ELE + ((size_t)(kt * 32 + nt0 + nn) * 64 + ln) * 8;
      *(f16x8*)(pool + OFF_W + (size_t)f * 1024 + ln * 16) = *(const f16x8*)(g_blob1 + so);
    }
  }
  const f16* loA = g_blob2 + (size_t)18 * MAT_ELE;
  __syncthreads();

  for (int t = 0; t < T_; ++t) {
    if (isA) {
      // ---- stage inputs (h-independent; overlaps producer) --------------
      for (int idx = tid; idx < 64 * KI; idx += NTHR) {
        int b = idx / KI, i = idx % KI;
        sInI[b * 8 + i] = inI[((size_t)b * KI + i) * T_ + t];
        sInC[b * 8 + i] = inC[((size_t)b * KI + i) * T_ + t];
      }
      // ---- WG gate: all 32 h-flags (u16, one cache line), wave 0 polls --
      if (wv == 0) {
        const u32 tgt = (u32)t;
        for (;;) {
          bool ok = true;
          if (lane < 16) {
            u32 v = lda32((const u32*)g_hflag + lane);
            ok = ((v & 0xffffu) >= tgt) && ((v >> 16) >= tgt);
          }
          if (__all(ok)) break;
          __builtin_amdgcn_s_sleep(4);
        }
      }
      __syncthreads();

      const int mh2 = wv >> 1, kh = wv & 1;
      const int ktBase = kh * 8;
      const u32* hbase = g_hp[(t + 1) & 1] + (size_t)(mh2 * 16 + l15) * H_ + quad * 8;

      // upfront batched h loads: 2 batches x 16 ld64
      u64 raw[2][4][4];
#pragma unroll
      for (int k2 = 0; k2 < 4; ++k2) {
        const u32* q = hbase + (size_t)(ktBase + k2) * 32;
        raw[0][k2][0] = lda64(q);     raw[0][k2][1] = lda64(q + 2);
        raw[0][k2][2] = lda64(q + 4); raw[0][k2][3] = lda64(q + 6);
      }
      f32x4 acc[2][4][2] = {};   // [mat][nn][0=hi,1=lo-correction]
      __builtin_amdgcn_s_setprio(1);
#pragma unroll
      for (int j = 0; j < 8; ++j) {
        if (j == 0) {
#pragma unroll
          for (int k2 = 0; k2 < 4; ++k2) {
            const u32* q = hbase + (size_t)(ktBase + 4 + k2) * 32;
            raw[1][k2][0] = lda64(q);     raw[1][k2][1] = lda64(q + 2);
            raw[1][k2][2] = lda64(q + 4); raw[1][k2][3] = lda64(q + 6);
          }
        }
        const int kt = ktBase + j;
        // lo-weight frags for this kt (L2-cached plain loads)
        f16x8 w2I[4], w2C[4];
#pragma unroll
        for (int nn = 0; nn < 4; ++nn) {
          w2I[nn] = ldw(loI, kt, nt0 + nn, lane);
          w2C[nn] = ldw(loC, kt, nt0 + nn, lane);
        }
        union { u64 q[4]; u32 w[8]; } r;
        r.q[0] = raw[j >> 2][j & 3][0]; r.q[1] = raw[j >> 2][j & 3][1];
        r.q[2] = raw[j >> 2][j & 3][2]; r.q[3] = raw[j >> 2][j & 3][3];
        union { f16x8 v; u16 s[8]; } ah, al;
#pragma unroll
        for (int jj = 0; jj < 8; ++jj) {
          ah.s[jj] = (u16)(r.w[jj] & 0xffffu);
          al.s[jj] = (u16)(r.w[jj] >> 16);
        }
#pragma unroll
        for (int mat = 0; mat < 2; ++mat)
#pragma unroll
          for (int nn = 0; nn < 4; ++nn) {
            int f = (mat * 16 + kt) * 4 + nn;
            f16x8 w1 = *(const f16x8*)(pool + OFF_W + (size_t)f * 1024 + lane * 16);
            f16x8 w2 = mat ? w2C[nn] : w2I[nn];
            acc[mat][nn][0] = mfma16(ah.v, w1, acc[mat][nn][0]);
            acc[mat][nn][1] = mfma16(ah.v, w2, acc[mat][nn][1]);
            acc[mat][nn][1] = mfma16(al.v, w1, acc[mat][nn][1]);
          }
      }
      __builtin_amdgcn_s_setprio(0);

      // ---- kh-half reduction, 2 rounds (mat0 then mat1) through 16KB ----
      f32x4 tot0[4];
      if (kh == 1) {
#pragma unroll
        for (int nn = 0; nn < 4; ++nn)
          *(f32x4*)(redf + mh2 * 1024 + (nn * 64 + lane) * 4) =
              acc[0][nn][0] + acc[0][nn][1] * (1.0f / 2048.0f);
      }
      __syncthreads();
      if (kh == 0) {
#pragma unroll
        for (int nn = 0; nn < 4; ++nn)
          tot0[nn] = acc[0][nn][0] + acc[0][nn][1] * (1.0f / 2048.0f) +
                     *(const f32x4*)(redf + mh2 * 1024 + (nn * 64 + lane) * 4);
      }
      __syncthreads();
      if (kh == 1) {
#pragma unroll
        for (int nn = 0; nn < 4; ++nn)
          *(f32x4*)(redf + mh2 * 1024 + (nn * 64 + lane) * 4) =
              acc[1][nn][0] + acc[1][nn][1] * (1.0f / 2048.0f);
      }
      __syncthreads();
      if (kh == 0) {
#pragma unroll
        for (int nn = 0; nn < 4; ++nn) {
          f32x4 tot1 = acc[1][nn][0] + acc[1][nn][1] * (1.0f / 2048.0f) +
                       *(const f32x4*)(redf + mh2 * 1024 + (nn * 64 + lane) * 4);
#pragma unroll
          for (int r4 = 0; r4 < 4; ++r4) {
            int brow = mh2 * 16 + quad * 4 + r4;
            int cc = nn * 16 + l15;
            float pre0 = tot0[nn][r4] + sbI[cc];
            float pre1 = tot1[r4] + sbC[cc];
            for (int i = 0; i < KI; ++i) {
              pre0 += sInI[brow * 8 + i] * sWI[i * 64 + cc];
              pre1 += sInC[brow * 8 + i] * sWC[i * 64 + cc];
            }
            if (kap == 8) {
              float fg = sigmoidf_(pre0);
              float og = sigmoidf_(pre1);
              u64 v = (u64)__builtin_bit_cast(u32, fg) |
                      ((u64)__builtin_bit_cast(u32, og) << 32);
              sta64(&g_fo[t & 1][(size_t)brow * H_ + C0A + cc], v);
            } else {
              float lv = sigmoidf_(pre0) * tanhf(pre1);
              f16 hi = (f16)lv;
              f16 lo = (f16)((lv - (float)hi) * 2048.0f);
              u32 pw = (u32)f16bits(hi) | ((u32)f16bits(lo) << 16);
              sta32(&g_lp[t & 1][((size_t)kap * B_ + brow) * H_ + C0A + cc], pw);
            }
          }
        }
      }
      __syncthreads();                 // drains all waves' vmcnt
      if (tid == 0) sta16(&g_lflag[wg], (u16)(t + 1));

    } else {
      // ================= B: u = tanh((l@W_a)*c + b_a), softmax, c/h ======
      // ---- WG gate: all 72 l-flags (u16, 3 cache lines), wave 0 polls ---
      if (wv == 0) {
        const u32 tgt = (u32)(t + 1);
        for (;;) {
          bool ok = true;
          if (lane < 36) {
            u32 v = lda32((const u32*)g_lflag + lane);
            ok = ((v & 0xffffu) >= tgt) && ((v >> 16) >= tgt);
          }
          if (__all(ok)) break;
          __builtin_amdgcn_s_sleep(4);
        }
      }
      __syncthreads();

      // fo prefetch (2 u64/thread: rows 0..7 and 8..15 of the tile)
      u64 foPre0 = lda64(&g_fo[t & 1][(size_t)(R0B + (tid >> 6)) * H_ + C0B + (tid & 63)]);
      u64 foPre1 = lda64(&g_fo[t & 1][(size_t)(R0B + 8 + (tid >> 6)) * H_ + C0B + (tid & 63)]);

      const int chP = wv >> 1, kh = wv & 1;
      const int ktBase = kh * 8;
      const int mrow = R0B + l15;
      const u32* lp = g_lp[t & 1];

      u64 raw[2][4][2][4];             // [batch][kt2][ch][q]
#pragma unroll
      for (int k2 = 0; k2 < 4; ++k2)
#pragma unroll
        for (int ch = 0; ch < 2; ++ch) {
          const u32* q = lp + ((size_t)(chP * 2 + ch) * B_ + mrow) * H_ +
                         (size_t)(ktBase + k2) * 32 + quad * 8;
          raw[0][k2][ch][0] = lda64(q);     raw[0][k2][ch][1] = lda64(q + 2);
          raw[0][k2][ch][2] = lda64(q + 4); raw[0][k2][ch][3] = lda64(q + 6);
        }
      f32x4 acc[2][4][2] = {};   // [ch][nn][hi/lo]
      __builtin_amdgcn_s_setprio(1);
#pragma unroll
      for (int j = 0; j < 8; ++j) {
        if (j == 0) {
#pragma unroll
          for (int k2 = 0; k2 < 4; ++k2)
#pragma unroll
            for (int ch = 0; ch < 2; ++ch) {
              const u32* q = lp + ((size_t)(chP * 2 + ch) * B_ + mrow) * H_ +
                             (size_t)(ktBase + 4 + k2) * 32 + quad * 8;
              raw[1][k2][ch][0] = lda64(q);     raw[1][k2][ch][1] = lda64(q + 2);
              raw[1][k2][ch][2] = lda64(q + 4); raw[1][k2][ch][3] = lda64(q + 6);
            }
        }
        const int kt = ktBase + j;
        f16x8 w2a[4];
#pragma unroll
        for (int nn = 0; nn < 4; ++nn) w2a[nn] = ldw(loA, kt, nt0 + nn, lane);
#pragma unroll
        for (int ch = 0; ch < 2; ++ch) {
          union { u64 q[4]; u32 w[8]; } r;
          r.q[0] = raw[j >> 2][j & 3][ch][0]; r.q[1] = raw[j >> 2][j & 3][ch][1];
          r.q[2] = raw[j >> 2][j & 3][ch][2]; r.q[3] = raw[j >> 2][j & 3][ch][3];
          if (kt == ktp || kt == ktp + 1) {
            // this fragment is half of the 16x64 l-tile needed by softmax
            u32* d = (u32*)(pool + OFF_SMX) +
                     ((size_t)(chP * 2 + ch) * 16 + l15) * 64 + (kt - ktp) * 32 + quad * 8;
            *(uint4*)d       = make_uint4(r.w[0], r.w[1], r.w[2], r.w[3]);
            *(uint4*)(d + 4) = make_uint4(r.w[4], r.w[5], r.w[6], r.w[7]);
          }
          union { f16x8 v; u16 s[8]; } ah, al;
#pragma unroll
          for (int jj = 0; jj < 8; ++jj) {
            ah.s[jj] = (u16)(r.w[jj] & 0xffffu);
            al.s[jj] = (u16)(r.w[jj] >> 16);
          }
#pragma unroll
          for (int nn = 0; nn < 4; ++nn) {
            int f = kt * 4 + nn;
            f16x8 w1 = *(const f16x8*)(pool + OFF_W + (size_t)f * 1024 + lane * 16);
            acc[ch][nn][0] = mfma16(ah.v, w1, acc[ch][nn][0]);
            acc[ch][nn][1] = mfma16(ah.v, w2a[nn], acc[ch][nn][1]);
            acc[ch][nn][1] = mfma16(al.v, w1, acc[ch][nn][1]);
          }
        }
      }
      __builtin_amdgcn_s_setprio(0);

      // ---- kh reduction + u compute, 2 rounds (ch0, ch1) ----------------
#pragma unroll
      for (int rch = 0; rch < 2; ++rch) {
        if (kh == 1) {
#pragma unroll
          for (int nn = 0; nn < 4; ++nn)
            *(f32x4*)(redf + chP * 1024 + (nn * 64 + lane) * 4) =
                acc[rch][nn][0] + acc[rch][nn][1] * (1.0f / 2048.0f);
        }
        __syncthreads();
        if (kh == 0) {
#pragma unroll
          for (int nn = 0; nn < 4; ++nn) {
            f32x4 dot = acc[rch][nn][0] + acc[rch][nn][1] * (1.0f / 2048.0f) +
                        *(const f32x4*)(redf + chP * 1024 + (nn * 64 + lane) * 4);
#pragma unroll
            for (int r4 = 0; r4 < 4; ++r4) {
              int bl = quad * 4 + r4;
              int cc = nn * 16 + l15;
              float uv = tanhf(dot[r4] * cl_[bl * 64 + cc] + sba[cc]);
              uf[(size_t)(chP * 2 + rch) * 1024 + bl * 64 + cc] = uv;
            }
          }
        }
        __syncthreads();
      }

      // softmax over 8 channels, c/h update, outputs (512 thr, 2 elems each)
#pragma unroll
      for (int e = 0; e < 2; ++e) {
        int idx = tid + e * 512;
        int bl = idx >> 6, cc = idx & 63;
        int bg = R0B + bl, cgl = C0B + cc;
        float uv[8], um = -1e30f;
#pragma unroll
        for (int k = 0; k < 8; ++k) {
          uv[k] = uf[(size_t)k * 1024 + bl * 64 + cc];
          um = fmaxf(um, uv[k]);
        }
        float ee[8], s = 0.0f;
#pragma unroll
        for (int k = 0; k < 8; ++k) { ee[k] = expf(uv[k] - um); s += ee[k]; }
        float inv = 1.0f / s;
        float L = 0.0f;
#pragma unroll
        for (int k = 0; k < 8; ++k) {
          u32 pw = *((const u32*)(pool + OFF_SMX) + (size_t)k * 1024 + bl * 64 + cc);
          float lvv = (float)bitsf16((u16)(pw & 0xffffu)) +
                      (float)bitsf16((u16)(pw >> 16)) * (1.0f / 2048.0f);
          L += ee[k] * inv * lvv;
        }
        u64 fo = e ? foPre1 : foPre0;
        float fg = __builtin_bit_cast(float, (u32)(fo & 0xffffffffu));
        float og = __builtin_bit_cast(float, (u32)(fo >> 32));
        float co = cl_[bl * 64 + cc];
        float cn = fg * co + L;
        float hn = og * tanhf(cn);
        cl_[bl * 64 + cc] = cn;
        f16 hh = (f16)hn;
        f16 hl = (f16)((hn - (float)hh) * 2048.0f);
        sta32(&g_hp[t & 1][(size_t)bg * H_ + cgl],
              (u32)f16bits(hh) | ((u32)f16bits(hl) << 16));
        p.out[(size_t)B_ * H_ + ((size_t)bg * T_ + t) * H_ + cgl] = hn;
        if (t == T_ - 1) p.out[(size_t)bg * H_ + cgl] = hn;
      }
      __syncthreads();                 // drains all waves' vmcnt
      if (tid == 0) sta16(&g_hflag[wg - NA_WG], (u16)(t + 1));
    }
  }
}

// ---------------------------------------------------------------------------
extern "C" void kernel_launch(void* const* d_in, const int* in_sizes, int n_in,
                              void* d_out, int out_size, void* d_ws, size_t ws_size,
                              hipStream_t stream) {
  (void)in_sizes; (void)n_in; (void)out_size; (void)d_ws; (void)ws_size;

  P p;
  p.Y = (const float*)d_in[0];
  for (int i = 0; i < 7; ++i) p.x[i] = (const float*)d_in[1 + i];
  p.W_i   = (const float*)d_in[8];  p.U_i   = (const float*)d_in[9];  p.b_i   = (const float*)d_in[10];
  p.W_f   = (const float*)d_in[11]; p.U_f   = (const float*)d_in[12]; p.b_f   = (const float*)d_in[13];
  p.W_c   = (const float*)d_in[14]; p.U_c   = (const float*)d_in[15]; p.b_c   = (const float*)d_in[16];
  p.W_o   = (const float*)d_in[17]; p.U_o   = (const float*)d_in[18]; p.b_o   = (const float*)d_in[19];
  p.W_i_x = (const float*)d_in[20]; p.U_i_x = (const float*)d_in[21]; p.b_i_x = (const float*)d_in[22];
  p.W_c_x = (const float*)d_in[23]; p.U_c_x = (const float*)d_in[24]; p.b_c_x = (const float*)d_in[25];
  p.W_a   = (const float*)d_in[26]; p.b_a   = (const float*)d_in[27];
  p.out   = (float*)d_out;

  prep_kernel<<<dim3(256), dim3(256), 0, stream>>>(p);

  void* kargs[] = { (void*)&p };
  hipError_t err = hipLaunchCooperativeKernel((void*)lstm_main, dim3(NWG), dim3(NTHR),
                                              kargs, 0, stream);
  if (err != hipSuccess) {
    // Fallback: plain launch. 104 blocks, 1/CU (LDS-bound) => co-resident on
    // 256 CUs; the flag protocol only needs co-residency, not coop launch.
    lstm_main<<<dim3(NWG), dim3(NTHR), 0, stream>>>(p);
  }
}

// Round 4
// 44371.143 us; speedup vs baseline: 2.2338x; 2.2338x over previous
//
#include <hip/hip_runtime.h>

// ============================================================================
// CustomMultiInputLSTM (B=64, H=512, T=1024, 7 aux) on gfx950 — round 9.
//
// History: r5 = 36.5ms (208 WGs, WG-gated dataflow, 32-col tiles).
// r6 = 52.8ms REGRESSION (per-wave scattered polling: LLC contention).
// r7 = 96.9ms REGRESSION (104 WGs: halved concurrency -> effective BW 0.3TB/s;
//      in-loop lo-weight loads; extra barriers).
// r8 = compile error (s_sleep needs constant literal arg). r9 = r8 fixed.
// Lesson: dur = sc1_traffic / eff_BW and eff_BW rises with concurrency.
// r9 = r5 structure EXACTLY, minus pure-overhead traffic:
//   (1) u16-packed flags, single-wave lda64 gate polls (A:2 lines, B:5 lines)
//       with backoff sleep — ~15x less poll traffic than r5's 64/144-thread
//       per-iteration scans.
//   (2) fo prefetched right after B's gate (kills a dependent LLC RT in the
//       scalar tail on the h-critical path).
//   (3) s_setprio(1) around MFMA clusters.
// All cross-WG data via agent-scope relaxed atomics (sc1, LLC-coherent).
// h/l packed as (f16hi | f16lo<<16) u32; split-f16 numerics, 3 MFMAs/pair.
// ============================================================================

typedef _Float16 f16;
typedef _Float16 f16x8 __attribute__((ext_vector_type(8)));
typedef float    f32x4 __attribute__((ext_vector_type(4)));
typedef unsigned int       u32;
typedef unsigned long long u64;
typedef unsigned short     u16;

#define DI static __device__ __forceinline__

constexpr int B_   = 64;
constexpr int H_   = 512;
constexpr int T_   = 1024;
constexpr int NWG  = 208;
constexpr int NTHR = 512;
constexpr int NA_WG = 144;   // 9 channels x 16 col-slices (32 cols)

constexpr size_t MAT_ELE = (size_t)16 * 32 * 64 * 8;   // f16 elems per matrix blob

// ---- LDS pool offsets (role-dependent) -------------------------------------
constexpr int OFF_W    = 0;        // A: 128 frags x 1KB = 128KB ; B: 64 frags
constexpr int OFF_SMX  = 65536;    // B: l-tile for softmax [8][16][32] u32 16KB
constexpr int OFF_UF   = 81920;    // B: u [8][16][32] f32 16KB
constexpr int OFF_CLDS = 98304;    // B: c [16][32] f32 2KB
constexpr int OFF_SBA  = 100352;   // B: b_a slice 128B
constexpr int OFF_RED  = 131072;   // both: 4 slots x 4KB kh-reduction
constexpr int OFF_SINI = 147456;   // A: [64][8] f32
constexpr int OFF_SINC = 149504;   // A: [64][8] f32
constexpr int OFF_SWI  = 151552;   // A: [8][32] f32
constexpr int OFF_SWC  = 152576;   // A: [8][32] f32
constexpr int OFF_SBI  = 153600;   // A: 32 f32
constexpr int OFF_SBC  = 153728;   // A: 32 f32
constexpr int POOL_SZ  = 153856;

// ---- static device scratch -------------------------------------------------
__device__ __align__(64) u16 g_hflag[64];    // u16 epoch flags (1 per B-WG)
__device__ __align__(64) u16 g_lflag[144];   // u16 epoch flags (1 per A-WG)
__device__ u32 g_hp[2][B_ * H_];        // packed h: hi | lo<<16, parity buffers
__device__ u32 g_lp[2][8 * B_ * H_];    // packed l
__device__ u64 g_fo[2][B_ * H_];        // (f32 f | f32 o << 32)
__device__ f16 g_blob1[19 * MAT_ELE];   // weight hi frags
__device__ f16 g_blob2[19 * MAT_ELE];   // weight lo frags (x2048)

struct P {
  const float* Y;
  const float* x[7];
  const float *W_i, *U_i, *b_i, *W_f, *U_f, *b_f;
  const float *W_c, *U_c, *b_c, *W_o, *U_o, *b_o;
  const float *W_i_x, *U_i_x, *b_i_x, *W_c_x, *U_c_x, *b_c_x;
  const float *W_a, *b_a;
  float* out;   // [64*512] h_T, then [64,1024,512] hidden_seq
};

DI f32x4 mfma16(f16x8 a, f16x8 b, f32x4 c) {
  return __builtin_amdgcn_mfma_f32_16x16x32_f16(a, b, c, 0, 0, 0);
}
DI float sigmoidf_(float x) { return 1.0f / (1.0f + expf(-x)); }

// agent-scope relaxed (sc1): bypass per-XCD L2, coherent at LLC
DI u32 lda32(const u32* p) {
  return __hip_atomic_load(p, __ATOMIC_RELAXED, __HIP_MEMORY_SCOPE_AGENT);
}
DI void sta32(u32* p, u32 v) {
  __hip_atomic_store(p, v, __ATOMIC_RELAXED, __HIP_MEMORY_SCOPE_AGENT);
}
DI u64 lda64(const void* p) {
  return __hip_atomic_load((const u64*)p, __ATOMIC_RELAXED, __HIP_MEMORY_SCOPE_AGENT);
}
DI void sta64(void* p, u64 v) {
  __hip_atomic_store((u64*)p, v, __ATOMIC_RELAXED, __HIP_MEMORY_SCOPE_AGENT);
}
DI void sta16(u16* p, u16 v) {
  __hip_atomic_store(p, v, __ATOMIC_RELAXED, __HIP_MEMORY_SCOPE_AGENT);
}
DI u16 f16bits(f16 h) { return __builtin_bit_cast(u16, h); }
DI f16  bitsf16(u16 b) { return __builtin_bit_cast(f16, b); }

// all four u16 halves of a packed u64 >= tgt ?
DI bool flags4_ge(u64 v, u32 tgt) {
  return ((u32)(v & 0xffffu) >= tgt) && ((u32)((v >> 16) & 0xffffu) >= tgt) &&
         ((u32)((v >> 32) & 0xffffu) >= tgt) && ((u32)(v >> 48) >= tgt);
}

// ---------------------------------------------------------------------------
// Prep: zero flags + h parity buffers; swizzle 19 [512x512] fp32 matrices
// into split-f16 MFMA B-fragment blobs.
// mat ids: 0=U_i, 1..7=U_i_x[k], 8=U_f, 9=U_c, 10..16=U_c_x[k], 17=U_o, 18=W_a
// ---------------------------------------------------------------------------
__global__ void __launch_bounds__(256) prep_kernel(P p) {
  const int gid = blockIdx.x * blockDim.x + threadIdx.x;
  const int nth = gridDim.x * blockDim.x;
  if (gid < 32) ((u32*)g_hflag)[gid] = 0u;   // 64 u16
  if (gid < 72) ((u32*)g_lflag)[gid] = 0u;   // 144 u16
  for (int i = gid; i < 2 * B_ * H_; i += nth) ((u32*)g_hp)[i] = 0u;

  const int lane = threadIdx.x & 63;
  const int wvg  = gid >> 6;
  const int nwv  = nth >> 6;
  for (int tile = wvg; tile < 19 * 16 * 32; tile += nwv) {
    const int mat = tile / (16 * 32);
    const int rem = tile % (16 * 32);
    const int kt = rem >> 5, nt = rem & 31;
    const float* src;
    if      (mat == 0)  src = p.U_i;
    else if (mat <  8)  src = p.U_i_x + (size_t)(mat - 1) * H_ * H_;
    else if (mat == 8)  src = p.U_f;
    else if (mat == 9)  src = p.U_c;
    else if (mat < 17)  src = p.U_c_x + (size_t)(mat - 10) * H_ * H_;
    else if (mat == 17) src = p.U_o;
    else                src = p.W_a;
    const int k0 = kt * 32 + (lane >> 4) * 8;     // B frag: k = quad*8+j
    const int n  = nt * 16 + (lane & 15);         //         n = lane&15
    f16x8 hv, lv;
#pragma unroll
    for (int j = 0; j < 8; ++j) {
      float v  = src[(size_t)(k0 + j) * H_ + n];
      f16   hh = (f16)v;
      hv[j] = hh;
      lv[j] = (f16)((v - (float)hh) * 2048.0f);
    }
    size_t off = (size_t)mat * MAT_ELE + ((size_t)(kt * 32 + nt) * 64 + lane) * 8;
    *(f16x8*)(g_blob1 + off) = hv;
    *(f16x8*)(g_blob2 + off) = lv;
  }
}

// ---------------------------------------------------------------------------
// Main persistent kernel: 208 WGs x 512 threads (8 waves).
//   A-WG (0..143): channel kap = wg>>4, cols C0A = (wg&15)*32.
//     wave = (mh2 = wv>>1 in 0..3: 16-row group, kh = wv&1: K half).
//     Each wave computes BOTH matrices (i-type mat0, c-type mat1).
//   B-WG (144..207): (R0B = 16-row tile, C0B = 32-col tile).
//     wave = (chPair = wv>>1, kh = wv&1).
// ---------------------------------------------------------------------------
__global__ void __launch_bounds__(NTHR, 2) lstm_main(P p) {
  const int wg   = blockIdx.x;
  const int tid  = threadIdx.x;
  const int lane = tid & 63;
  const int wv   = tid >> 6;
  const int quad = lane >> 4;
  const int l15  = lane & 15;

  __shared__ __align__(16) char pool[POOL_SZ];
  float* sInI = (float*)(pool + OFF_SINI);
  float* sInC = (float*)(pool + OFF_SINC);
  float* sWI  = (float*)(pool + OFF_SWI);
  float* sWC  = (float*)(pool + OFF_SWC);
  float* sbI  = (float*)(pool + OFF_SBI);
  float* sbC  = (float*)(pool + OFF_SBC);
  float* sba  = (float*)(pool + OFF_SBA);
  float* cl_  = (float*)(pool + OFF_CLDS);
  float* redf = (float*)(pool + OFF_RED);
  float* uf   = (float*)(pool + OFF_UF);

  const bool isA = (wg < NA_WG);

  int kap = 0, C0A = 0, KI = 8, nt0 = 0;
  const float* inI = p.Y;
  const float* inC = p.Y;
  int R0B = 0, C0B = 0;

  if (isA) {
    kap = wg >> 4;
    C0A = (wg & 15) * 32;
    nt0 = C0A >> 4;
    KI  = (kap == 0 || kap == 8) ? 8 : 3;
    int matI, matC;
    const float *WIs, *bIs, *WCs, *bCs;
    if (kap == 0)      { WIs = p.W_i; bIs = p.b_i; WCs = p.W_c; bCs = p.b_c; matI = 0; matC = 9; }
    else if (kap == 8) { WIs = p.W_f; bIs = p.b_f; WCs = p.W_o; bCs = p.b_o; matI = 8; matC = 17; }
    else {
      WIs = p.W_i_x + (size_t)(kap - 1) * 3 * H_;
      bIs = p.b_i_x + (size_t)(kap - 1) * H_;
      WCs = p.W_c_x + (size_t)(kap - 1) * 3 * H_;
      bCs = p.b_c_x + (size_t)(kap - 1) * H_;
      inI = (kap == 1) ? p.x[0] : p.x[1];   // xi = [x1, x2, x2, x2, x2, x2, x2]
      inC = p.x[kap - 1];                   // xc = [x1 .. x7]
      matI = kap; matC = 9 + kap;
    }
    for (int idx = tid; idx < KI * 32; idx += NTHR) {
      int i = idx >> 5, c = idx & 31;
      sWI[i * 32 + c] = WIs[(size_t)i * H_ + C0A + c];
      sWC[i * 32 + c] = WCs[(size_t)i * H_ + C0A + c];
    }
    if (tid < 32) { sbI[tid] = bIs[C0A + tid]; sbC[tid] = bCs[C0A + tid]; }
    // stage both matrices' 32-col weight slices: 128 frags x 1KB
    for (int c = tid; c < 8192; c += NTHR) {
      int frag = c >> 6, ln = c & 63;
      int half = frag & 1, nn = (frag >> 1) & 1, kt = (frag >> 2) & 15, ms = frag >> 6;
      int mat = ms ? matC : matI;
      size_t so = (size_t)mat * MAT_ELE + ((size_t)(kt * 32 + nt0 + nn) * 64 + ln) * 8;
      *(f16x8*)(pool + OFF_W + (size_t)frag * 1024 + ln * 16) =
          *(const f16x8*)((half ? g_blob2 : g_blob1) + so);
    }
  } else {
    int w2 = wg - NA_WG;
    R0B = (w2 >> 4) * 16;
    C0B = (w2 & 15) * 32;
    nt0 = C0B >> 4;
    if (tid < 32) sba[tid] = p.b_a[C0B + tid];
    for (int idx = tid; idx < 512; idx += NTHR) cl_[idx] = 0.0f;
    // W_a slice: 64 frags x 1KB
    for (int c = tid; c < 4096; c += NTHR) {
      int frag = c >> 6, ln = c & 63;
      int half = frag & 1, nn = (frag >> 1) & 1, kt = frag >> 2;
      size_t so = (size_t)18 * MAT_ELE + ((size_t)(kt * 32 + nt0 + nn) * 64 + ln) * 8;
      *(f16x8*)(pool + OFF_W + (size_t)frag * 1024 + ln * 16) =
          *(const f16x8*)((half ? g_blob2 : g_blob1) + so);
    }
  }
  __syncthreads();

  for (int t = 0; t < T_; ++t) {
    if (isA) {
      // ---- stage inputs (h-independent; overlaps producer) --------------
      for (int idx = tid; idx < 64 * KI; idx += NTHR) {
        int b = idx / KI, i = idx % KI;
        sInI[b * 8 + i] = inI[((size_t)b * KI + i) * T_ + t];
        sInC[b * 8 + i] = inC[((size_t)b * KI + i) * T_ + t];
      }
      // ---- WG gate: 64 u16 h-flags, wave 0 polls 16 lda64, backoff ------
      if (wv == 0) {
        const u32 tgt = (u32)t;
        int spin = 0;
        for (;;) {
          bool ok = true;
          if (lane < 16) ok = flags4_ge(lda64((const u64*)g_hflag + lane), tgt);
          if (__all(ok)) break;
          if (spin > 2) __builtin_amdgcn_s_sleep(8);
          else          __builtin_amdgcn_s_sleep(1);
          ++spin;
        }
      }
      __syncthreads();

      const int mh2 = wv >> 1, kh = wv & 1;
      const int ktBase = kh * 8;
      const u32* hp = g_hp[(t + 1) & 1];
      const u32* hbase = hp + (size_t)(mh2 * 16 + l15) * H_ + quad * 8;

      // upfront batched loads: 2 batches x 16 ld64 (all independent)
      u64 raw[2][4][4];
#pragma unroll
      for (int k2 = 0; k2 < 4; ++k2) {
        const u32* q = hbase + (ktBase + k2) * 32;
        raw[0][k2][0] = lda64(q);     raw[0][k2][1] = lda64(q + 2);
        raw[0][k2][2] = lda64(q + 4); raw[0][k2][3] = lda64(q + 6);
      }
      f32x4 acc[2][2][2] = {};   // [mat][nn][0=hi,1=lo-correction]
      __builtin_amdgcn_s_setprio(1);
      for (int g = 0; g < 2; ++g) {
        if (g == 0) {
#pragma unroll
          for (int k2 = 0; k2 < 4; ++k2) {
            const u32* q = hbase + (ktBase + 4 + k2) * 32;
            raw[1][k2][0] = lda64(q);     raw[1][k2][1] = lda64(q + 2);
            raw[1][k2][2] = lda64(q + 4); raw[1][k2][3] = lda64(q + 6);
          }
        }
#pragma unroll
        for (int k2 = 0; k2 < 4; ++k2) {
          int kt = ktBase + g * 4 + k2;
          union { u64 q[4]; u32 w[8]; } r;
          r.q[0] = raw[g][k2][0]; r.q[1] = raw[g][k2][1];
          r.q[2] = raw[g][k2][2]; r.q[3] = raw[g][k2][3];
          union { f16x8 v; u16 s[8]; } ah, al;
#pragma unroll
          for (int j = 0; j < 8; ++j) {
            ah.s[j] = (u16)(r.w[j] & 0xffffu);
            al.s[j] = (u16)(r.w[j] >> 16);
          }
#pragma unroll
          for (int mat = 0; mat < 2; ++mat)
#pragma unroll
            for (int nn = 0; nn < 2; ++nn) {
              int f = ((mat * 16 + kt) * 2 + nn) * 2;
              f16x8 w1 = *(const f16x8*)(pool + OFF_W + (size_t)f * 1024 + lane * 16);
              f16x8 w2 = *(const f16x8*)(pool + OFF_W + (size_t)(f + 1) * 1024 + lane * 16);
              acc[mat][nn][0] = mfma16(ah.v, w1, acc[mat][nn][0]);
              acc[mat][nn][1] = mfma16(ah.v, w2, acc[mat][nn][1]);
              acc[mat][nn][1] = mfma16(al.v, w1, acc[mat][nn][1]);
            }
        }
      }
      __builtin_amdgcn_s_setprio(0);

      // kh-half reduction through LDS
      if (kh == 1) {
#pragma unroll
        for (int mat = 0; mat < 2; ++mat)
#pragma unroll
          for (int nn = 0; nn < 2; ++nn) {
            f32x4 comb = acc[mat][nn][0] + acc[mat][nn][1] * (1.0f / 2048.0f);
            *(f32x4*)(redf + mh2 * 1024 + ((mat * 2 + nn) * 64 + lane) * 4) = comb;
          }
      }
      __syncthreads();

      if (kh == 0) {
#pragma unroll
        for (int nn = 0; nn < 2; ++nn) {
          f32x4 tot[2];
#pragma unroll
          for (int mat = 0; mat < 2; ++mat) {
            f32x4 oth = *(const f32x4*)(redf + mh2 * 1024 + ((mat * 2 + nn) * 64 + lane) * 4);
            tot[mat] = acc[mat][nn][0] + acc[mat][nn][1] * (1.0f / 2048.0f) + oth;
          }
#pragma unroll
          for (int r4 = 0; r4 < 4; ++r4) {
            int brow = mh2 * 16 + quad * 4 + r4;
            int cc = nn * 16 + l15;
            float pre0 = tot[0][r4] + sbI[cc];
            float pre1 = tot[1][r4] + sbC[cc];
            for (int i = 0; i < KI; ++i) {
              pre0 += sInI[brow * 8 + i] * sWI[i * 32 + cc];
              pre1 += sInC[brow * 8 + i] * sWC[i * 32 + cc];
            }
            if (kap == 8) {
              float fg = sigmoidf_(pre0);
              float og = sigmoidf_(pre1);
              u64 v = (u64)__builtin_bit_cast(u32, fg) |
                      ((u64)__builtin_bit_cast(u32, og) << 32);
              sta64(&g_fo[t & 1][(size_t)brow * H_ + C0A + cc], v);
            } else {
              float lv = sigmoidf_(pre0) * tanhf(pre1);
              f16 hi = (f16)lv;
              f16 lo = (f16)((lv - (float)hi) * 2048.0f);
              u32 pw = (u32)f16bits(hi) | ((u32)f16bits(lo) << 16);
              sta32(&g_lp[t & 1][((size_t)kap * B_ + brow) * H_ + C0A + cc], pw);
            }
          }
        }
      }
      __syncthreads();                 // drains all waves' vmcnt
      if (tid == 0) sta16(&g_lflag[wg], (u16)(t + 1));

    } else {
      // ================= B: u = tanh((l@W_a)*c + b_a), softmax, c/h ======
      // ---- WG gate: 144 u16 l-flags, wave 0 polls 36 lda64, backoff -----
      if (wv == 0) {
        const u32 tgt = (u32)(t + 1);
        int spin = 0;
        for (;;) {
          bool ok = true;
          if (lane < 36) ok = flags4_ge(lda64((const u64*)g_lflag + lane), tgt);
          if (__all(ok)) break;
          if (spin > 2) __builtin_amdgcn_s_sleep(8);
          else          __builtin_amdgcn_s_sleep(1);
          ++spin;
        }
      }
      __syncthreads();

      // fo prefetch (1 u64/thread), consumed in the scalar tail
      u64 foPre = lda64(&g_fo[t & 1][(size_t)(R0B + (tid >> 5)) * H_ + C0B + (tid & 31)]);

      const int chP = wv >> 1, kh = wv & 1;
      const int ktBase = kh * 8;
      const int mrow = R0B + l15;
      const u32* lp = g_lp[t & 1];
      const int smxkt = C0B >> 5;      // the kt whose k-range == this col tile

      u64 raw[2][4][2][4];             // [buf][kt2][ch][q]
#pragma unroll
      for (int k2 = 0; k2 < 4; ++k2)
#pragma unroll
        for (int ch = 0; ch < 2; ++ch) {
          const u32* q = lp + ((size_t)(chP * 2 + ch) * B_ + mrow) * H_ +
                         (ktBase + k2) * 32 + quad * 8;
          raw[0][k2][ch][0] = lda64(q);     raw[0][k2][ch][1] = lda64(q + 2);
          raw[0][k2][ch][2] = lda64(q + 4); raw[0][k2][ch][3] = lda64(q + 6);
        }
      f32x4 acc[2][2][2] = {};   // [ch][nn][hi/lo]
      __builtin_amdgcn_s_setprio(1);
      for (int g = 0; g < 2; ++g) {
        if (g == 0) {
#pragma unroll
          for (int k2 = 0; k2 < 4; ++k2)
#pragma unroll
            for (int ch = 0; ch < 2; ++ch) {
              const u32* q = lp + ((size_t)(chP * 2 + ch) * B_ + mrow) * H_ +
                             (ktBase + 4 + k2) * 32 + quad * 8;
              raw[1][k2][ch][0] = lda64(q);     raw[1][k2][ch][1] = lda64(q + 2);
              raw[1][k2][ch][2] = lda64(q + 4); raw[1][k2][ch][3] = lda64(q + 6);
            }
        }
#pragma unroll
        for (int k2 = 0; k2 < 4; ++k2) {
          int kt = ktBase + g * 4 + k2;
#pragma unroll
          for (int ch = 0; ch < 2; ++ch) {
            union { u64 q[4]; u32 w[8]; } r;
            r.q[0] = raw[g][k2][ch][0]; r.q[1] = raw[g][k2][ch][1];
            r.q[2] = raw[g][k2][ch][2]; r.q[3] = raw[g][k2][ch][3];
            if (kt == smxkt) {
              // this fragment IS the 16x32 l-tile needed by softmax
              u32* d = (u32*)(pool + OFF_SMX +
                       (((size_t)(chP * 2 + ch) * 16 + l15) * 32 + quad * 8) * 4);
              *(uint4*)d       = make_uint4(r.w[0], r.w[1], r.w[2], r.w[3]);
              *(uint4*)(d + 4) = make_uint4(r.w[4], r.w[5], r.w[6], r.w[7]);
            }
            union { f16x8 v; u16 s[8]; } ah, al;
#pragma unroll
            for (int j = 0; j < 8; ++j) {
              ah.s[j] = (u16)(r.w[j] & 0xffffu);
              al.s[j] = (u16)(r.w[j] >> 16);
            }
#pragma unroll
            for (int nn = 0; nn < 2; ++nn) {
              int f = (kt * 2 + nn) * 2;
              f16x8 w1 = *(const f16x8*)(pool + OFF_W + (size_t)f * 1024 + lane * 16);
              f16x8 w2 = *(const f16x8*)(pool + OFF_W + (size_t)(f + 1) * 1024 + lane * 16);
              acc[ch][nn][0] = mfma16(ah.v, w1, acc[ch][nn][0]);
              acc[ch][nn][1] = mfma16(ah.v, w2, acc[ch][nn][1]);
              acc[ch][nn][1] = mfma16(al.v, w1, acc[ch][nn][1]);
            }
          }
        }
      }
      __builtin_amdgcn_s_setprio(0);

      if (kh == 1) {
#pragma unroll
        for (int ch = 0; ch < 2; ++ch)
#pragma unroll
          for (int nn = 0; nn < 2; ++nn) {
            f32x4 comb = acc[ch][nn][0] + acc[ch][nn][1] * (1.0f / 2048.0f);
            *(f32x4*)(redf + chP * 1024 + ((ch * 2 + nn) * 64 + lane) * 4) = comb;
          }
      }
      __syncthreads();
      if (kh == 0) {
#pragma unroll
        for (int ch = 0; ch < 2; ++ch)
#pragma unroll
          for (int nn = 0; nn < 2; ++nn) {
            f32x4 oth = *(const f32x4*)(redf + chP * 1024 + ((ch * 2 + nn) * 64 + lane) * 4);
            f32x4 dot = acc[ch][nn][0] + acc[ch][nn][1] * (1.0f / 2048.0f) + oth;
#pragma unroll
            for (int r4 = 0; r4 < 4; ++r4) {
              int bl = quad * 4 + r4;
              int cc = nn * 16 + l15;
              float uv = tanhf(dot[r4] * cl_[bl * 32 + cc] + sba[cc]);
              uf[(chP * 2 + ch) * 512 + bl * 32 + cc] = uv;
            }
          }
      }
      __syncthreads();

      // softmax over 8 channels, c/h update, outputs (512 thr, 1 elem each)
      {
        int bl = tid >> 5, cc = tid & 31;
        int bg = R0B + bl, cgl = C0B + cc;
        float uv[8], um = -1e30f;
#pragma unroll
        for (int k = 0; k < 8; ++k) { uv[k] = uf[k * 512 + tid]; um = fmaxf(um, uv[k]); }
        float e[8], s = 0.0f;
#pragma unroll
        for (int k = 0; k < 8; ++k) { e[k] = expf(uv[k] - um); s += e[k]; }
        float inv = 1.0f / s;
        float L = 0.0f;
#pragma unroll
        for (int k = 0; k < 8; ++k) {
          u32 pw = *(const u32*)(pool + OFF_SMX + ((size_t)k * 512 + tid) * 4);
          float lvv = (float)bitsf16((u16)(pw & 0xffffu)) +
                      (float)bitsf16((u16)(pw >> 16)) * (1.0f / 2048.0f);
          L += e[k] * inv * lvv;
        }
        float fg = __builtin_bit_cast(float, (u32)(foPre & 0xffffffffu));
        float og = __builtin_bit_cast(float, (u32)(foPre >> 32));
        float co = cl_[bl * 32 + cc];
        float cn = fg * co + L;
        float hn = og * tanhf(cn);
        cl_[bl * 32 + cc] = cn;
        f16 hh = (f16)hn;
        f16 hl = (f16)((hn - (float)hh) * 2048.0f);
        sta32(&g_hp[t & 1][(size_t)bg * H_ + cgl],
              (u32)f16bits(hh) | ((u32)f16bits(hl) << 16));
        p.out[(size_t)B_ * H_ + ((size_t)bg * T_ + t) * H_ + cgl] = hn;
        if (t == T_ - 1) p.out[(size_t)bg * H_ + cgl] = hn;
      }
      __syncthreads();                 // drains all waves' vmcnt
      if (tid == 0) sta16(&g_hflag[wg - NA_WG], (u16)(t + 1));
    }
  }
}

// ---------------------------------------------------------------------------
extern "C" void kernel_launch(void* const* d_in, const int* in_sizes, int n_in,
                              void* d_out, int out_size, void* d_ws, size_t ws_size,
                              hipStream_t stream) {
  (void)in_sizes; (void)n_in; (void)out_size; (void)d_ws; (void)ws_size;

  P p;
  p.Y = (const float*)d_in[0];
  for (int i = 0; i < 7; ++i) p.x[i] = (const float*)d_in[1 + i];
  p.W_i   = (const float*)d_in[8];  p.U_i   = (const float*)d_in[9];  p.b_i   = (const float*)d_in[10];
  p.W_f   = (const float*)d_in[11]; p.U_f   = (const float*)d_in[12]; p.b_f   = (const float*)d_in[13];
  p.W_c   = (const float*)d_in[14]; p.U_c   = (const float*)d_in[15]; p.b_c   = (const float*)d_in[16];
  p.W_o   = (const float*)d_in[17]; p.U_o   = (const float*)d_in[18]; p.b_o   = (const float*)d_in[19];
  p.W_i_x = (const float*)d_in[20]; p.U_i_x = (const float*)d_in[21]; p.b_i_x = (const float*)d_in[22];
  p.W_c_x = (const float*)d_in[23]; p.U_c_x = (const float*)d_in[24]; p.b_c_x = (const float*)d_in[25];
  p.W_a   = (const float*)d_in[26]; p.b_a   = (const float*)d_in[27];
  p.out   = (float*)d_out;

  prep_kernel<<<dim3(256), dim3(256), 0, stream>>>(p);

  void* kargs[] = { (void*)&p };
  hipError_t err = hipLaunchCooperativeKernel((void*)lstm_main, dim3(NWG), dim3(NTHR),
                                              kargs, 0, stream);
  if (err != hipSuccess) {
    // Fallback: plain launch. 208 blocks, 1/CU (LDS-bound) => co-resident on
    // 256 CUs; the flag protocol only needs co-residency, not coop launch.
    lstm_main<<<dim3(NWG), dim3(NTHR), 0, stream>>>(p);
  }
}

// Round 5
// 25965.945 us; speedup vs baseline: 3.8171x; 1.7088x over previous
//
#include <hip/hip_runtime.h>

// ============================================================================
// CustomMultiInputLSTM (B=64, H=512, T=1024, 7 aux) on gfx950 — round 10.
//
// History: r5 36.5ms (208 WG dataflow) / r6 52.8 (scattered poll REGR) /
// r7 96.9 (104 WG REGR, concurrency) / r9 41.7 (poll diet: hbm 40->6.7GB,
// time flat => NOT volume-bound; LLC request-path bound).
// r10 = r9 + consumer-coalesced FRAGMENT LAYOUT for h and l:
//   h stored as hF[mh2][kt][j][lane] u64, l as lF[ch][mh2][kt][j][lane].
//   Every consumer lda64 instruction now reads 512B fully-contiguous
//   (64 lanes x 8B), 100% line utilization, ~2x fewer LLC line requests
//   vs row-major (16 half-used lines per instr). Register contents are
//   bit-identical to r9 — only addresses changed. Producer stores remain
//   scattered sta32 (same count as r9).
// All cross-WG data via agent-scope relaxed atomics (sc1, LLC-coherent).
// h/l packed as (f16hi | f16lo<<16) u32; split-f16 numerics, 3 MFMAs/pair.
// ============================================================================

typedef _Float16 f16;
typedef _Float16 f16x8 __attribute__((ext_vector_type(8)));
typedef float    f32x4 __attribute__((ext_vector_type(4)));
typedef unsigned int       u32;
typedef unsigned long long u64;
typedef unsigned short     u16;

#define DI static __device__ __forceinline__

constexpr int B_   = 64;
constexpr int H_   = 512;
constexpr int T_   = 1024;
constexpr int NWG  = 208;
constexpr int NTHR = 512;
constexpr int NA_WG = 144;   // 9 channels x 16 col-slices (32 cols)

constexpr size_t MAT_ELE = (size_t)16 * 32 * 64 * 8;   // f16 elems per matrix blob

// ---- LDS pool offsets (role-dependent) -------------------------------------
constexpr int OFF_W    = 0;        // A: 128 frags x 1KB = 128KB ; B: 64 frags
constexpr int OFF_SMX  = 65536;    // B: l-tile for softmax [8][16][32] u32 16KB
constexpr int OFF_UF   = 81920;    // B: u [8][16][32] f32 16KB
constexpr int OFF_CLDS = 98304;    // B: c [16][32] f32 2KB
constexpr int OFF_SBA  = 100352;   // B: b_a slice 128B
constexpr int OFF_RED  = 131072;   // both: 4 slots x 4KB kh-reduction
constexpr int OFF_SINI = 147456;   // A: [64][8] f32
constexpr int OFF_SINC = 149504;   // A: [64][8] f32
constexpr int OFF_SWI  = 151552;   // A: [8][32] f32
constexpr int OFF_SWC  = 152576;   // A: [8][32] f32
constexpr int OFF_SBI  = 153600;   // A: 32 f32
constexpr int OFF_SBC  = 153728;   // A: 32 f32
constexpr int POOL_SZ  = 153856;

// ---- static device scratch -------------------------------------------------
// hF layout: [parity][mh2(4)][kt(16)][j(4)][lane(64)] u64
//   element: row = mh2*16 + (lane&15), k = kt*32 + (lane>>4)*8 + j*2 + {0,1}
// lF layout: [parity][ch(8)][mh2(4)][kt(16)][j(4)][lane(64)] u64
__device__ __align__(64) u16 g_hflag[64];    // u16 epoch flags (1 per B-WG)
__device__ __align__(64) u16 g_lflag[144];   // u16 epoch flags (1 per A-WG)
__device__ u32 g_hp[2][B_ * H_];        // packed h fragment blob (128KB/parity)
__device__ u32 g_lp[2][8 * B_ * H_];    // packed l fragment blob (1MB/parity)
__device__ u64 g_fo[2][B_ * H_];        // (f32 f | f32 o << 32), row-major
__device__ f16 g_blob1[19 * MAT_ELE];   // weight hi frags
__device__ f16 g_blob2[19 * MAT_ELE];   // weight lo frags (x2048)

struct P {
  const float* Y;
  const float* x[7];
  const float *W_i, *U_i, *b_i, *W_f, *U_f, *b_f;
  const float *W_c, *U_c, *b_c, *W_o, *U_o, *b_o;
  const float *W_i_x, *U_i_x, *b_i_x, *W_c_x, *U_c_x, *b_c_x;
  const float *W_a, *b_a;
  float* out;   // [64*512] h_T, then [64,1024,512] hidden_seq
};

DI f32x4 mfma16(f16x8 a, f16x8 b, f32x4 c) {
  return __builtin_amdgcn_mfma_f32_16x16x32_f16(a, b, c, 0, 0, 0);
}
DI float sigmoidf_(float x) { return 1.0f / (1.0f + expf(-x)); }

// agent-scope relaxed (sc1): bypass per-XCD L2, coherent at LLC
DI u32 lda32(const u32* p) {
  return __hip_atomic_load(p, __ATOMIC_RELAXED, __HIP_MEMORY_SCOPE_AGENT);
}
DI void sta32(u32* p, u32 v) {
  __hip_atomic_store(p, v, __ATOMIC_RELAXED, __HIP_MEMORY_SCOPE_AGENT);
}
DI u64 lda64(const void* p) {
  return __hip_atomic_load((const u64*)p, __ATOMIC_RELAXED, __HIP_MEMORY_SCOPE_AGENT);
}
DI void sta64(void* p, u64 v) {
  __hip_atomic_store((u64*)p, v, __ATOMIC_RELAXED, __HIP_MEMORY_SCOPE_AGENT);
}
DI void sta16(u16* p, u16 v) {
  __hip_atomic_store(p, v, __ATOMIC_RELAXED, __HIP_MEMORY_SCOPE_AGENT);
}
DI u16 f16bits(f16 h) { return __builtin_bit_cast(u16, h); }
DI f16  bitsf16(u16 b) { return __builtin_bit_cast(f16, b); }

// all four u16 halves of a packed u64 >= tgt ?
DI bool flags4_ge(u64 v, u32 tgt) {
  return ((u32)(v & 0xffffu) >= tgt) && ((u32)((v >> 16) & 0xffffu) >= tgt) &&
         ((u32)((v >> 32) & 0xffffu) >= tgt) && ((u32)(v >> 48) >= tgt);
}

// ---------------------------------------------------------------------------
// Prep: zero flags + h parity buffers; swizzle 19 [512x512] fp32 matrices
// into split-f16 MFMA B-fragment blobs.
// mat ids: 0=U_i, 1..7=U_i_x[k], 8=U_f, 9=U_c, 10..16=U_c_x[k], 17=U_o, 18=W_a
// ---------------------------------------------------------------------------
__global__ void __launch_bounds__(256) prep_kernel(P p) {
  const int gid = blockIdx.x * blockDim.x + threadIdx.x;
  const int nth = gridDim.x * blockDim.x;
  if (gid < 32) ((u32*)g_hflag)[gid] = 0u;   // 64 u16
  if (gid < 72) ((u32*)g_lflag)[gid] = 0u;   // 144 u16
  for (int i = gid; i < 2 * B_ * H_; i += nth) ((u32*)g_hp)[i] = 0u;

  const int lane = threadIdx.x & 63;
  const int wvg  = gid >> 6;
  const int nwv  = nth >> 6;
  for (int tile = wvg; tile < 19 * 16 * 32; tile += nwv) {
    const int mat = tile / (16 * 32);
    const int rem = tile % (16 * 32);
    const int kt = rem >> 5, nt = rem & 31;
    const float* src;
    if      (mat == 0)  src = p.U_i;
    else if (mat <  8)  src = p.U_i_x + (size_t)(mat - 1) * H_ * H_;
    else if (mat == 8)  src = p.U_f;
    else if (mat == 9)  src = p.U_c;
    else if (mat < 17)  src = p.U_c_x + (size_t)(mat - 10) * H_ * H_;
    else if (mat == 17) src = p.U_o;
    else                src = p.W_a;
    const int k0 = kt * 32 + (lane >> 4) * 8;     // B frag: k = quad*8+j
    const int n  = nt * 16 + (lane & 15);         //         n = lane&15
    f16x8 hv, lv;
#pragma unroll
    for (int j = 0; j < 8; ++j) {
      float v  = src[(size_t)(k0 + j) * H_ + n];
      f16   hh = (f16)v;
      hv[j] = hh;
      lv[j] = (f16)((v - (float)hh) * 2048.0f);
    }
    size_t off = (size_t)mat * MAT_ELE + ((size_t)(kt * 32 + nt) * 64 + lane) * 8;
    *(f16x8*)(g_blob1 + off) = hv;
    *(f16x8*)(g_blob2 + off) = lv;
  }
}

// ---------------------------------------------------------------------------
// Main persistent kernel: 208 WGs x 512 threads (8 waves).
//   A-WG (0..143): channel kap = wg>>4, cols C0A = (wg&15)*32.
//     wave = (mh2 = wv>>1 in 0..3: 16-row group, kh = wv&1: K half).
//     Each wave computes BOTH matrices (i-type mat0, c-type mat1).
//   B-WG (144..207): (R0B = 16-row tile, C0B = 32-col tile).
//     wave = (chPair = wv>>1, kh = wv&1).
// ---------------------------------------------------------------------------
__global__ void __launch_bounds__(NTHR, 2) lstm_main(P p) {
  const int wg   = blockIdx.x;
  const int tid  = threadIdx.x;
  const int lane = tid & 63;
  const int wv   = tid >> 6;
  const int quad = lane >> 4;
  const int l15  = lane & 15;

  __shared__ __align__(16) char pool[POOL_SZ];
  float* sInI = (float*)(pool + OFF_SINI);
  float* sInC = (float*)(pool + OFF_SINC);
  float* sWI  = (float*)(pool + OFF_SWI);
  float* sWC  = (float*)(pool + OFF_SWC);
  float* sbI  = (float*)(pool + OFF_SBI);
  float* sbC  = (float*)(pool + OFF_SBC);
  float* sba  = (float*)(pool + OFF_SBA);
  float* cl_  = (float*)(pool + OFF_CLDS);
  float* redf = (float*)(pool + OFF_RED);
  float* uf   = (float*)(pool + OFF_UF);

  const bool isA = (wg < NA_WG);

  int kap = 0, C0A = 0, KI = 8, nt0 = 0;
  const float* inI = p.Y;
  const float* inC = p.Y;
  int R0B = 0, C0B = 0;

  if (isA) {
    kap = wg >> 4;
    C0A = (wg & 15) * 32;
    nt0 = C0A >> 4;
    KI  = (kap == 0 || kap == 8) ? 8 : 3;
    int matI, matC;
    const float *WIs, *bIs, *WCs, *bCs;
    if (kap == 0)      { WIs = p.W_i; bIs = p.b_i; WCs = p.W_c; bCs = p.b_c; matI = 0; matC = 9; }
    else if (kap == 8) { WIs = p.W_f; bIs = p.b_f; WCs = p.W_o; bCs = p.b_o; matI = 8; matC = 17; }
    else {
      WIs = p.W_i_x + (size_t)(kap - 1) * 3 * H_;
      bIs = p.b_i_x + (size_t)(kap - 1) * H_;
      WCs = p.W_c_x + (size_t)(kap - 1) * 3 * H_;
      bCs = p.b_c_x + (size_t)(kap - 1) * H_;
      inI = (kap == 1) ? p.x[0] : p.x[1];   // xi = [x1, x2, x2, x2, x2, x2, x2]
      inC = p.x[kap - 1];                   // xc = [x1 .. x7]
      matI = kap; matC = 9 + kap;
    }
    for (int idx = tid; idx < KI * 32; idx += NTHR) {
      int i = idx >> 5, c = idx & 31;
      sWI[i * 32 + c] = WIs[(size_t)i * H_ + C0A + c];
      sWC[i * 32 + c] = WCs[(size_t)i * H_ + C0A + c];
    }
    if (tid < 32) { sbI[tid] = bIs[C0A + tid]; sbC[tid] = bCs[C0A + tid]; }
    // stage both matrices' 32-col weight slices: 128 frags x 1KB
    for (int c = tid; c < 8192; c += NTHR) {
      int frag = c >> 6, ln = c & 63;
      int half = frag & 1, nn = (frag >> 1) & 1, kt = (frag >> 2) & 15, ms = frag >> 6;
      int mat = ms ? matC : matI;
      size_t so = (size_t)mat * MAT_ELE + ((size_t)(kt * 32 + nt0 + nn) * 64 + ln) * 8;
      *(f16x8*)(pool + OFF_W + (size_t)frag * 1024 + ln * 16) =
          *(const f16x8*)((half ? g_blob2 : g_blob1) + so);
    }
  } else {
    int w2 = wg - NA_WG;
    R0B = (w2 >> 4) * 16;
    C0B = (w2 & 15) * 32;
    nt0 = C0B >> 4;
    if (tid < 32) sba[tid] = p.b_a[C0B + tid];
    for (int idx = tid; idx < 512; idx += NTHR) cl_[idx] = 0.0f;
    // W_a slice: 64 frags x 1KB
    for (int c = tid; c < 4096; c += NTHR) {
      int frag = c >> 6, ln = c & 63;
      int half = frag & 1, nn = (frag >> 1) & 1, kt = frag >> 2;
      size_t so = (size_t)18 * MAT_ELE + ((size_t)(kt * 32 + nt0 + nn) * 64 + ln) * 8;
      *(f16x8*)(pool + OFF_W + (size_t)frag * 1024 + ln * 16) =
          *(const f16x8*)((half ? g_blob2 : g_blob1) + so);
    }
  }
  __syncthreads();

  for (int t = 0; t < T_; ++t) {
    if (isA) {
      // ---- stage inputs (h-independent; overlaps producer) --------------
      for (int idx = tid; idx < 64 * KI; idx += NTHR) {
        int b = idx / KI, i = idx % KI;
        sInI[b * 8 + i] = inI[((size_t)b * KI + i) * T_ + t];
        sInC[b * 8 + i] = inC[((size_t)b * KI + i) * T_ + t];
      }
      // ---- WG gate: 64 u16 h-flags, wave 0 polls 16 lda64, backoff ------
      if (wv == 0) {
        const u32 tgt = (u32)t;
        int spin = 0;
        for (;;) {
          bool ok = true;
          if (lane < 16) ok = flags4_ge(lda64((const u64*)g_hflag + lane), tgt);
          if (__all(ok)) break;
          if (spin > 2) __builtin_amdgcn_s_sleep(8);
          else          __builtin_amdgcn_s_sleep(1);
          ++spin;
        }
      }
      __syncthreads();

      const int mh2 = wv >> 1, kh = wv & 1;
      const int ktBase = kh * 8;
      // hF fragment base: [mh2][kt=ktBase][j=0][lane] —每 lda64 reads 512B contig
      const u64* hF = (const u64*)g_hp[(t + 1) & 1] +
                      ((size_t)(mh2 * 16 + ktBase) * 4) * 64 + lane;

      // upfront batched loads: 2 batches x 16 ld64 (all contiguous-512B instrs)
      u64 raw[2][4][4];
#pragma unroll
      for (int k2 = 0; k2 < 4; ++k2) {
#pragma unroll
        for (int j = 0; j < 4; ++j)
          raw[0][k2][j] = lda64(hF + (size_t)(k2 * 4 + j) * 64);
      }
      f32x4 acc[2][2][2] = {};   // [mat][nn][0=hi,1=lo-correction]
      __builtin_amdgcn_s_setprio(1);
      for (int g = 0; g < 2; ++g) {
        if (g == 0) {
#pragma unroll
          for (int k2 = 0; k2 < 4; ++k2) {
#pragma unroll
            for (int j = 0; j < 4; ++j)
              raw[1][k2][j] = lda64(hF + (size_t)((4 + k2) * 4 + j) * 64);
          }
        }
#pragma unroll
        for (int k2 = 0; k2 < 4; ++k2) {
          int kt = ktBase + g * 4 + k2;
          union { u64 q[4]; u32 w[8]; } r;
          r.q[0] = raw[g][k2][0]; r.q[1] = raw[g][k2][1];
          r.q[2] = raw[g][k2][2]; r.q[3] = raw[g][k2][3];
          union { f16x8 v; u16 s[8]; } ah, al;
#pragma unroll
          for (int j = 0; j < 8; ++j) {
            ah.s[j] = (u16)(r.w[j] & 0xffffu);
            al.s[j] = (u16)(r.w[j] >> 16);
          }
#pragma unroll
          for (int mat = 0; mat < 2; ++mat)
#pragma unroll
            for (int nn = 0; nn < 2; ++nn) {
              int f = ((mat * 16 + kt) * 2 + nn) * 2;
              f16x8 w1 = *(const f16x8*)(pool + OFF_W + (size_t)f * 1024 + lane * 16);
              f16x8 w2 = *(const f16x8*)(pool + OFF_W + (size_t)(f + 1) * 1024 + lane * 16);
              acc[mat][nn][0] = mfma16(ah.v, w1, acc[mat][nn][0]);
              acc[mat][nn][1] = mfma16(ah.v, w2, acc[mat][nn][1]);
              acc[mat][nn][1] = mfma16(al.v, w1, acc[mat][nn][1]);
            }
        }
      }
      __builtin_amdgcn_s_setprio(0);

      // kh-half reduction through LDS
      if (kh == 1) {
#pragma unroll
        for (int mat = 0; mat < 2; ++mat)
#pragma unroll
          for (int nn = 0; nn < 2; ++nn) {
            f32x4 comb = acc[mat][nn][0] + acc[mat][nn][1] * (1.0f / 2048.0f);
            *(f32x4*)(redf + mh2 * 1024 + ((mat * 2 + nn) * 64 + lane) * 4) = comb;
          }
      }
      __syncthreads();

      if (kh == 0) {
        const int ktA = wg & 15;       // this WG's l col-tile
#pragma unroll
        for (int nn = 0; nn < 2; ++nn) {
          f32x4 tot[2];
#pragma unroll
          for (int mat = 0; mat < 2; ++mat) {
            f32x4 oth = *(const f32x4*)(redf + mh2 * 1024 + ((mat * 2 + nn) * 64 + lane) * 4);
            tot[mat] = acc[mat][nn][0] + acc[mat][nn][1] * (1.0f / 2048.0f) + oth;
          }
#pragma unroll
          for (int r4 = 0; r4 < 4; ++r4) {
            int brow = mh2 * 16 + quad * 4 + r4;
            int cc = nn * 16 + l15;
            float pre0 = tot[0][r4] + sbI[cc];
            float pre1 = tot[1][r4] + sbC[cc];
            for (int i = 0; i < KI; ++i) {
              pre0 += sInI[brow * 8 + i] * sWI[i * 32 + cc];
              pre1 += sInC[brow * 8 + i] * sWC[i * 32 + cc];
            }
            if (kap == 8) {
              float fg = sigmoidf_(pre0);
              float og = sigmoidf_(pre1);
              u64 v = (u64)__builtin_bit_cast(u32, fg) |
                      ((u64)__builtin_bit_cast(u32, og) << 32);
              sta64(&g_fo[t & 1][(size_t)brow * H_ + C0A + cc], v);
            } else {
              float lv = sigmoidf_(pre0) * tanhf(pre1);
              f16 hi = (f16)lv;
              f16 lo = (f16)((lv - (float)hi) * 2048.0f);
              u32 pw = (u32)f16bits(hi) | ((u32)f16bits(lo) << 16);
              // lF[ch=kap][mh2][ktA][jl][lane = (cc>>3)*16 + quad*4+r4] half
              int quadl = cc >> 3, jl = (cc & 7) >> 1, half = cc & 1;
              size_t idx = (((((size_t)kap * 4 + mh2) * 16 + ktA) * 4 + jl) * 64 +
                            quadl * 16 + quad * 4 + r4) * 2 + half;
              sta32((u32*)g_lp[t & 1] + idx, pw);
            }
          }
        }
      }
      __syncthreads();                 // drains all waves' vmcnt
      if (tid == 0) sta16(&g_lflag[wg], (u16)(t + 1));

    } else {
      // ================= B: u = tanh((l@W_a)*c + b_a), softmax, c/h ======
      // ---- WG gate: 144 u16 l-flags, wave 0 polls 36 lda64, backoff -----
      if (wv == 0) {
        const u32 tgt = (u32)(t + 1);
        int spin = 0;
        for (;;) {
          bool ok = true;
          if (lane < 36) ok = flags4_ge(lda64((const u64*)g_lflag + lane), tgt);
          if (__all(ok)) break;
          if (spin > 2) __builtin_amdgcn_s_sleep(8);
          else          __builtin_amdgcn_s_sleep(1);
          ++spin;
        }
      }
      __syncthreads();

      // fo prefetch (1 u64/thread), consumed in the scalar tail
      u64 foPre = lda64(&g_fo[t & 1][(size_t)(R0B + (tid >> 5)) * H_ + C0B + (tid & 31)]);

      const int chP = wv >> 1, kh = wv & 1;
      const int ktBase = kh * 8;
      const int mh2B = R0B >> 4;
      const u64* lF = (const u64*)g_lp[t & 1];
      const int smxkt = C0B >> 5;      // the kt whose k-range == this col tile

      // per-ch fragment bases (contiguous-512B per lda64)
      const u64* lb[2];
#pragma unroll
      for (int ch = 0; ch < 2; ++ch)
        lb[ch] = lF + ((((size_t)(chP * 2 + ch) * 4 + mh2B) * 16 + ktBase) * 4) * 64 + lane;

      u64 raw[2][4][2][4];             // [buf][kt2][ch][j]
#pragma unroll
      for (int k2 = 0; k2 < 4; ++k2)
#pragma unroll
        for (int ch = 0; ch < 2; ++ch) {
#pragma unroll
          for (int j = 0; j < 4; ++j)
            raw[0][k2][ch][j] = lda64(lb[ch] + (size_t)(k2 * 4 + j) * 64);
        }
      f32x4 acc[2][2][2] = {};   // [ch][nn][hi/lo]
      __builtin_amdgcn_s_setprio(1);
      for (int g = 0; g < 2; ++g) {
        if (g == 0) {
#pragma unroll
          for (int k2 = 0; k2 < 4; ++k2)
#pragma unroll
            for (int ch = 0; ch < 2; ++ch) {
#pragma unroll
              for (int j = 0; j < 4; ++j)
                raw[1][k2][ch][j] = lda64(lb[ch] + (size_t)((4 + k2) * 4 + j) * 64);
            }
        }
#pragma unroll
        for (int k2 = 0; k2 < 4; ++k2) {
          int kt = ktBase + g * 4 + k2;
#pragma unroll
          for (int ch = 0; ch < 2; ++ch) {
            union { u64 q[4]; u32 w[8]; } r;
            r.q[0] = raw[g][k2][ch][0]; r.q[1] = raw[g][k2][ch][1];
            r.q[2] = raw[g][k2][ch][2]; r.q[3] = raw[g][k2][ch][3];
            if (kt == smxkt) {
              // this fragment IS the 16x32 l-tile needed by softmax
              u32* d = (u32*)(pool + OFF_SMX +
                       (((size_t)(chP * 2 + ch) * 16 + l15) * 32 + quad * 8) * 4);
              *(uint4*)d       = make_uint4(r.w[0], r.w[1], r.w[2], r.w[3]);
              *(uint4*)(d + 4) = make_uint4(r.w[4], r.w[5], r.w[6], r.w[7]);
            }
            union { f16x8 v; u16 s[8]; } ah, al;
#pragma unroll
            for (int j = 0; j < 8; ++j) {
              ah.s[j] = (u16)(r.w[j] & 0xffffu);
              al.s[j] = (u16)(r.w[j] >> 16);
            }
#pragma unroll
            for (int nn = 0; nn < 2; ++nn) {
              int f = (kt * 2 + nn) * 2;
              f16x8 w1 = *(const f16x8*)(pool + OFF_W + (size_t)f * 1024 + lane * 16);
              f16x8 w2 = *(const f16x8*)(pool + OFF_W + (size_t)(f + 1) * 1024 + lane * 16);
              acc[ch][nn][0] = mfma16(ah.v, w1, acc[ch][nn][0]);
              acc[ch][nn][1] = mfma16(ah.v, w2, acc[ch][nn][1]);
              acc[ch][nn][1] = mfma16(al.v, w1, acc[ch][nn][1]);
            }
          }
        }
      }
      __builtin_amdgcn_s_setprio(0);

      if (kh == 1) {
#pragma unroll
        for (int ch = 0; ch < 2; ++ch)
#pragma unroll
          for (int nn = 0; nn < 2; ++nn) {
            f32x4 comb = acc[ch][nn][0] + acc[ch][nn][1] * (1.0f / 2048.0f);
            *(f32x4*)(redf + chP * 1024 + ((ch * 2 + nn) * 64 + lane) * 4) = comb;
          }
      }
      __syncthreads();
      if (kh == 0) {
#pragma unroll
        for (int ch = 0; ch < 2; ++ch)
#pragma unroll
          for (int nn = 0; nn < 2; ++nn) {
            f32x4 oth = *(const f32x4*)(redf + chP * 1024 + ((ch * 2 + nn) * 64 + lane) * 4);
            f32x4 dot = acc[ch][nn][0] + acc[ch][nn][1] * (1.0f / 2048.0f) + oth;
#pragma unroll
            for (int r4 = 0; r4 < 4; ++r4) {
              int bl = quad * 4 + r4;
              int cc = nn * 16 + l15;
              float uv = tanhf(dot[r4] * cl_[bl * 32 + cc] + sba[cc]);
              uf[(chP * 2 + ch) * 512 + bl * 32 + cc] = uv;
            }
          }
      }
      __syncthreads();

      // softmax over 8 channels, c/h update, outputs (512 thr, 1 elem each)
      {
        int bl = tid >> 5, cc = tid & 31;
        int bg = R0B + bl, cgl = C0B + cc;
        float uv[8], um = -1e30f;
#pragma unroll
        for (int k = 0; k < 8; ++k) { uv[k] = uf[k * 512 + tid]; um = fmaxf(um, uv[k]); }
        float e[8], s = 0.0f;
#pragma unroll
        for (int k = 0; k < 8; ++k) { e[k] = expf(uv[k] - um); s += e[k]; }
        float inv = 1.0f / s;
        float L = 0.0f;
#pragma unroll
        for (int k = 0; k < 8; ++k) {
          u32 pw = *(const u32*)(pool + OFF_SMX + ((size_t)k * 512 + tid) * 4);
          float lvv = (float)bitsf16((u16)(pw & 0xffffu)) +
                      (float)bitsf16((u16)(pw >> 16)) * (1.0f / 2048.0f);
          L += e[k] * inv * lvv;
        }
        float fg = __builtin_bit_cast(float, (u32)(foPre & 0xffffffffu));
        float og = __builtin_bit_cast(float, (u32)(foPre >> 32));
        float co = cl_[bl * 32 + cc];
        float cn = fg * co + L;
        float hn = og * tanhf(cn);
        cl_[bl * 32 + cc] = cn;
        f16 hh = (f16)hn;
        f16 hl = (f16)((hn - (float)hh) * 2048.0f);
        // hF[mh2 = R0B>>4][kt = C0B>>5][j=(cc&7)>>1][lane=(cc>>3)*16+bl] half
        {
          size_t idx = ((((size_t)(R0B >> 4) * 16 + (C0B >> 5)) * 4 + ((cc & 7) >> 1)) * 64 +
                        (cc >> 3) * 16 + bl) * 2 + (cc & 1);
          sta32((u32*)g_hp[t & 1] + idx,
                (u32)f16bits(hh) | ((u32)f16bits(hl) << 16));
        }
        p.out[(size_t)B_ * H_ + ((size_t)bg * T_ + t) * H_ + cgl] = hn;
        if (t == T_ - 1) p.out[(size_t)bg * H_ + cgl] = hn;
      }
      __syncthreads();                 // drains all waves' vmcnt
      if (tid == 0) sta16(&g_hflag[wg - NA_WG], (u16)(t + 1));
    }
  }
}

// ---------------------------------------------------------------------------
extern "C" void kernel_launch(void* const* d_in, const int* in_sizes, int n_in,
                              void* d_out, int out_size, void* d_ws, size_t ws_size,
                              hipStream_t stream) {
  (void)in_sizes; (void)n_in; (void)out_size; (void)d_ws; (void)ws_size;

  P p;
  p.Y = (const float*)d_in[0];
  for (int i = 0; i < 7; ++i) p.x[i] = (const float*)d_in[1 + i];
  p.W_i   = (const float*)d_in[8];  p.U_i   = (const float*)d_in[9];  p.b_i   = (const float*)d_in[10];
  p.W_f   = (const float*)d_in[11]; p.U_f   = (const float*)d_in[12]; p.b_f   = (const float*)d_in[13];
  p.W_c   = (const float*)d_in[14]; p.U_c   = (const float*)d_in[15]; p.b_c   = (const float*)d_in[16];
  p.W_o   = (const float*)d_in[17]; p.U_o   = (const float*)d_in[18]; p.b_o   = (const float*)d_in[19];
  p.W_i_x = (const float*)d_in[20]; p.U_i_x = (const float*)d_in[21]; p.b_i_x = (const float*)d_in[22];
  p.W_c_x = (const float*)d_in[23]; p.U_c_x = (const float*)d_in[24]; p.b_c_x = (const float*)d_in[25];
  p.W_a   = (const float*)d_in[26]; p.b_a   = (const float*)d_in[27];
  p.out   = (float*)d_out;

  prep_kernel<<<dim3(256), dim3(256), 0, stream>>>(p);

  void* kargs[] = { (void*)&p };
  hipError_t err = hipLaunchCooperativeKernel((void*)lstm_main, dim3(NWG), dim3(NTHR),
                                              kargs, 0, stream);
  if (err != hipSuccess) {
    // Fallback: plain launch. 208 blocks, 1/CU (LDS-bound) => co-resident on
    // 256 CUs; the flag protocol only needs co-residency, not coop launch.
    lstm_main<<<dim3(NWG), dim3(NTHR), 0, stream>>>(p);
  }
}

// Round 6
// 24986.211 us; speedup vs baseline: 3.9668x; 1.0392x over previous
//
#include <hip/hip_runtime.h>

// ============================================================================
// CustomMultiInputLSTM (B=64, H=512, T=1024, 7 aux) on gfx950 — round 11.
//
// History: r5 36.5ms / r6 52.8 REGR (scattered poll) / r7 96.9 REGR
// (concurrency) / r9 41.7 (poll diet; proved not volume-bound) /
// r10 26.0ms WIN: consumer-coalesced fragment layout (full-line reads,
// LLC request-path was the binder; MfmaUtil 2.6->4.0).
// r10 counters: WRITE_SIZE tripled to 4.9GB — producer stores are now the
// scattered side (l: 2048 x 4B sta32/WG -> ~16 partial-line RMWs per wave
// instr; h: 512 x 4B).
// r11 = r10 + producer-coalesced stores (mirror of r10's read fix):
//   stage l (8KB) / h (2KB) in LDS in fragment order, then store with
//   fully-coalesced 512B/instr sta64 wave stores (16 line-writes per A-WG,
//   4 per B-WG). +1 barrier per phase. Reads and arithmetic bit-identical.
//   Poll backoff sleep 8 -> 4.
// All cross-WG data via agent-scope relaxed atomics (sc1, LLC-coherent).
// h/l packed as (f16hi | f16lo<<16) u32; split-f16 numerics, 3 MFMAs/pair.
// ============================================================================

typedef _Float16 f16;
typedef _Float16 f16x8 __attribute__((ext_vector_type(8)));
typedef float    f32x4 __attribute__((ext_vector_type(4)));
typedef unsigned int       u32;
typedef unsigned long long u64;
typedef unsigned short     u16;

#define DI static __device__ __forceinline__

constexpr int B_   = 64;
constexpr int H_   = 512;
constexpr int T_   = 1024;
constexpr int NWG  = 208;
constexpr int NTHR = 512;
constexpr int NA_WG = 144;   // 9 channels x 16 col-slices (32 cols)

constexpr size_t MAT_ELE = (size_t)16 * 32 * 64 * 8;   // f16 elems per matrix blob

// ---- LDS pool offsets (role-dependent) -------------------------------------
constexpr int OFF_W    = 0;        // A: 128 frags x 1KB = 128KB ; B: 64 frags
constexpr int OFF_SMX  = 65536;    // B: l-tile for softmax [8][16][32] u32 16KB
constexpr int OFF_UF   = 81920;    // B: u [8][16][32] f32 16KB
constexpr int OFF_CLDS = 98304;    // B: c [16][32] f32 2KB
constexpr int OFF_SBA  = 100352;   // B: b_a slice 128B
constexpr int OFF_RED  = 131072;   // both: 4 slots x 4KB kh-reduction
constexpr int OFF_SINI = 147456;   // A: [64][8] f32
constexpr int OFF_SINC = 149504;   // A: [64][8] f32
constexpr int OFF_SWI  = 151552;   // A: [8][32] f32
constexpr int OFF_SWC  = 152576;   // A: [8][32] f32
constexpr int OFF_SBI  = 153600;   // A: 32 f32
constexpr int OFF_SBC  = 153728;   // A: 32 f32
constexpr int OFF_STG  = 153856;   // A: 8KB l-stage ; B: 2KB h-stage
constexpr int POOL_SZ  = 162048;   // <= 160KB (163840)

// ---- static device scratch -------------------------------------------------
// hF layout: [parity][mh2(4)][kt(16)][j(4)][lane(64)] u64
//   element: row = mh2*16 + (lane&15), k = kt*32 + (lane>>4)*8 + j*2 + {0,1}
// lF layout: [parity][ch(8)][mh2(4)][kt(16)][j(4)][lane(64)] u64
__device__ __align__(64) u16 g_hflag[64];    // u16 epoch flags (1 per B-WG)
__device__ __align__(64) u16 g_lflag[144];   // u16 epoch flags (1 per A-WG)
__device__ u32 g_hp[2][B_ * H_];        // packed h fragment blob (128KB/parity)
__device__ u32 g_lp[2][8 * B_ * H_];    // packed l fragment blob (1MB/parity)
__device__ u64 g_fo[2][B_ * H_];        // (f32 f | f32 o << 32), row-major
__device__ f16 g_blob1[19 * MAT_ELE];   // weight hi frags
__device__ f16 g_blob2[19 * MAT_ELE];   // weight lo frags (x2048)

struct P {
  const float* Y;
  const float* x[7];
  const float *W_i, *U_i, *b_i, *W_f, *U_f, *b_f;
  const float *W_c, *U_c, *b_c, *W_o, *U_o, *b_o;
  const float *W_i_x, *U_i_x, *b_i_x, *W_c_x, *U_c_x, *b_c_x;
  const float *W_a, *b_a;
  float* out;   // [64*512] h_T, then [64,1024,512] hidden_seq
};

DI f32x4 mfma16(f16x8 a, f16x8 b, f32x4 c) {
  return __builtin_amdgcn_mfma_f32_16x16x32_f16(a, b, c, 0, 0, 0);
}
DI float sigmoidf_(float x) { return 1.0f / (1.0f + expf(-x)); }

// agent-scope relaxed (sc1): bypass per-XCD L2, coherent at LLC
DI u32 lda32(const u32* p) {
  return __hip_atomic_load(p, __ATOMIC_RELAXED, __HIP_MEMORY_SCOPE_AGENT);
}
DI void sta32(u32* p, u32 v) {
  __hip_atomic_store(p, v, __ATOMIC_RELAXED, __HIP_MEMORY_SCOPE_AGENT);
}
DI u64 lda64(const void* p) {
  return __hip_atomic_load((const u64*)p, __ATOMIC_RELAXED, __HIP_MEMORY_SCOPE_AGENT);
}
DI void sta64(void* p, u64 v) {
  __hip_atomic_store((u64*)p, v, __ATOMIC_RELAXED, __HIP_MEMORY_SCOPE_AGENT);
}
DI void sta16(u16* p, u16 v) {
  __hip_atomic_store(p, v, __ATOMIC_RELAXED, __HIP_MEMORY_SCOPE_AGENT);
}
DI u16 f16bits(f16 h) { return __builtin_bit_cast(u16, h); }
DI f16  bitsf16(u16 b) { return __builtin_bit_cast(f16, b); }

// all four u16 halves of a packed u64 >= tgt ?
DI bool flags4_ge(u64 v, u32 tgt) {
  return ((u32)(v & 0xffffu) >= tgt) && ((u32)((v >> 16) & 0xffffu) >= tgt) &&
         ((u32)((v >> 32) & 0xffffu) >= tgt) && ((u32)(v >> 48) >= tgt);
}

// ---------------------------------------------------------------------------
// Prep: zero flags + h parity buffers; swizzle 19 [512x512] fp32 matrices
// into split-f16 MFMA B-fragment blobs.
// mat ids: 0=U_i, 1..7=U_i_x[k], 8=U_f, 9=U_c, 10..16=U_c_x[k], 17=U_o, 18=W_a
// ---------------------------------------------------------------------------
__global__ void __launch_bounds__(256) prep_kernel(P p) {
  const int gid = blockIdx.x * blockDim.x + threadIdx.x;
  const int nth = gridDim.x * blockDim.x;
  if (gid < 32) ((u32*)g_hflag)[gid] = 0u;   // 64 u16
  if (gid < 72) ((u32*)g_lflag)[gid] = 0u;   // 144 u16
  for (int i = gid; i < 2 * B_ * H_; i += nth) ((u32*)g_hp)[i] = 0u;

  const int lane = threadIdx.x & 63;
  const int wvg  = gid >> 6;
  const int nwv  = nth >> 6;
  for (int tile = wvg; tile < 19 * 16 * 32; tile += nwv) {
    const int mat = tile / (16 * 32);
    const int rem = tile % (16 * 32);
    const int kt = rem >> 5, nt = rem & 31;
    const float* src;
    if      (mat == 0)  src = p.U_i;
    else if (mat <  8)  src = p.U_i_x + (size_t)(mat - 1) * H_ * H_;
    else if (mat == 8)  src = p.U_f;
    else if (mat == 9)  src = p.U_c;
    else if (mat < 17)  src = p.U_c_x + (size_t)(mat - 10) * H_ * H_;
    else if (mat == 17) src = p.U_o;
    else                src = p.W_a;
    const int k0 = kt * 32 + (lane >> 4) * 8;     // B frag: k = quad*8+j
    const int n  = nt * 16 + (lane & 15);         //         n = lane&15
    f16x8 hv, lv;
#pragma unroll
    for (int j = 0; j < 8; ++j) {
      float v  = src[(size_t)(k0 + j) * H_ + n];
      f16   hh = (f16)v;
      hv[j] = hh;
      lv[j] = (f16)((v - (float)hh) * 2048.0f);
    }
    size_t off = (size_t)mat * MAT_ELE + ((size_t)(kt * 32 + nt) * 64 + lane) * 8;
    *(f16x8*)(g_blob1 + off) = hv;
    *(f16x8*)(g_blob2 + off) = lv;
  }
}

// ---------------------------------------------------------------------------
// Main persistent kernel: 208 WGs x 512 threads (8 waves).
//   A-WG (0..143): channel kap = wg>>4, cols C0A = (wg&15)*32.
//     wave = (mh2 = wv>>1 in 0..3: 16-row group, kh = wv&1: K half).
//     Each wave computes BOTH matrices (i-type mat0, c-type mat1).
//   B-WG (144..207): (R0B = 16-row tile, C0B = 32-col tile).
//     wave = (chPair = wv>>1, kh = wv&1).
// ---------------------------------------------------------------------------
__global__ void __launch_bounds__(NTHR, 2) lstm_main(P p) {
  const int wg   = blockIdx.x;
  const int tid  = threadIdx.x;
  const int lane = tid & 63;
  const int wv   = tid >> 6;
  const int quad = lane >> 4;
  const int l15  = lane & 15;

  __shared__ __align__(16) char pool[POOL_SZ];
  float* sInI = (float*)(pool + OFF_SINI);
  float* sInC = (float*)(pool + OFF_SINC);
  float* sWI  = (float*)(pool + OFF_SWI);
  float* sWC  = (float*)(pool + OFF_SWC);
  float* sbI  = (float*)(pool + OFF_SBI);
  float* sbC  = (float*)(pool + OFF_SBC);
  float* sba  = (float*)(pool + OFF_SBA);
  float* cl_  = (float*)(pool + OFF_CLDS);
  float* redf = (float*)(pool + OFF_RED);
  float* uf   = (float*)(pool + OFF_UF);
  u32*   stg  = (u32*)(pool + OFF_STG);

  const bool isA = (wg < NA_WG);

  int kap = 0, C0A = 0, KI = 8, nt0 = 0, ktA = 0;
  const float* inI = p.Y;
  const float* inC = p.Y;
  int R0B = 0, C0B = 0;

  if (isA) {
    kap = wg >> 4;
    C0A = (wg & 15) * 32;
    nt0 = C0A >> 4;
    ktA = wg & 15;
    KI  = (kap == 0 || kap == 8) ? 8 : 3;
    int matI, matC;
    const float *WIs, *bIs, *WCs, *bCs;
    if (kap == 0)      { WIs = p.W_i; bIs = p.b_i; WCs = p.W_c; bCs = p.b_c; matI = 0; matC = 9; }
    else if (kap == 8) { WIs = p.W_f; bIs = p.b_f; WCs = p.W_o; bCs = p.b_o; matI = 8; matC = 17; }
    else {
      WIs = p.W_i_x + (size_t)(kap - 1) * 3 * H_;
      bIs = p.b_i_x + (size_t)(kap - 1) * H_;
      WCs = p.W_c_x + (size_t)(kap - 1) * 3 * H_;
      bCs = p.b_c_x + (size_t)(kap - 1) * H_;
      inI = (kap == 1) ? p.x[0] : p.x[1];   // xi = [x1, x2, x2, x2, x2, x2, x2]
      inC = p.x[kap - 1];                   // xc = [x1 .. x7]
      matI = kap; matC = 9 + kap;
    }
    for (int idx = tid; idx < KI * 32; idx += NTHR) {
      int i = idx >> 5, c = idx & 31;
      sWI[i * 32 + c] = WIs[(size_t)i * H_ + C0A + c];
      sWC[i * 32 + c] = WCs[(size_t)i * H_ + C0A + c];
    }
    if (tid < 32) { sbI[tid] = bIs[C0A + tid]; sbC[tid] = bCs[C0A + tid]; }
    // stage both matrices' 32-col weight slices: 128 frags x 1KB
    for (int c = tid; c < 8192; c += NTHR) {
      int frag = c >> 6, ln = c & 63;
      int half = frag & 1, nn = (frag >> 1) & 1, kt = (frag >> 2) & 15, ms = frag >> 6;
      int mat = ms ? matC : matI;
      size_t so = (size_t)mat * MAT_ELE + ((size_t)(kt * 32 + nt0 + nn) * 64 + ln) * 8;
      *(f16x8*)(pool + OFF_W + (size_t)frag * 1024 + ln * 16) =
          *(const f16x8*)((half ? g_blob2 : g_blob1) + so);
    }
  } else {
    int w2 = wg - NA_WG;
    R0B = (w2 >> 4) * 16;
    C0B = (w2 & 15) * 32;
    nt0 = C0B >> 4;
    if (tid < 32) sba[tid] = p.b_a[C0B + tid];
    for (int idx = tid; idx < 512; idx += NTHR) cl_[idx] = 0.0f;
    // W_a slice: 64 frags x 1KB
    for (int c = tid; c < 4096; c += NTHR) {
      int frag = c >> 6, ln = c & 63;
      int half = frag & 1, nn = (frag >> 1) & 1, kt = frag >> 2;
      size_t so = (size_t)18 * MAT_ELE + ((size_t)(kt * 32 + nt0 + nn) * 64 + ln) * 8;
      *(f16x8*)(pool + OFF_W + (size_t)frag * 1024 + ln * 16) =
          *(const f16x8*)((half ? g_blob2 : g_blob1) + so);
    }
  }
  __syncthreads();

  for (int t = 0; t < T_; ++t) {
    if (isA) {
      // ---- stage inputs (h-independent; overlaps producer) --------------
      for (int idx = tid; idx < 64 * KI; idx += NTHR) {
        int b = idx / KI, i = idx % KI;
        sInI[b * 8 + i] = inI[((size_t)b * KI + i) * T_ + t];
        sInC[b * 8 + i] = inC[((size_t)b * KI + i) * T_ + t];
      }
      // ---- WG gate: 64 u16 h-flags, wave 0 polls 16 lda64, backoff ------
      if (wv == 0) {
        const u32 tgt = (u32)t;
        int spin = 0;
        for (;;) {
          bool ok = true;
          if (lane < 16) ok = flags4_ge(lda64((const u64*)g_hflag + lane), tgt);
          if (__all(ok)) break;
          if (spin > 2) __builtin_amdgcn_s_sleep(4);
          else          __builtin_amdgcn_s_sleep(1);
          ++spin;
        }
      }
      __syncthreads();

      const int mh2 = wv >> 1, kh = wv & 1;
      const int ktBase = kh * 8;
      // hF fragment base: [mh2][kt=ktBase][j=0][lane] — each lda64 reads 512B contig
      const u64* hF = (const u64*)g_hp[(t + 1) & 1] +
                      ((size_t)(mh2 * 16 + ktBase) * 4) * 64 + lane;

      // upfront batched loads: 2 batches x 16 ld64 (all contiguous-512B instrs)
      u64 raw[2][4][4];
#pragma unroll
      for (int k2 = 0; k2 < 4; ++k2) {
#pragma unroll
        for (int j = 0; j < 4; ++j)
          raw[0][k2][j] = lda64(hF + (size_t)(k2 * 4 + j) * 64);
      }
      f32x4 acc[2][2][2] = {};   // [mat][nn][0=hi,1=lo-correction]
      __builtin_amdgcn_s_setprio(1);
      for (int g = 0; g < 2; ++g) {
        if (g == 0) {
#pragma unroll
          for (int k2 = 0; k2 < 4; ++k2) {
#pragma unroll
            for (int j = 0; j < 4; ++j)
              raw[1][k2][j] = lda64(hF + (size_t)((4 + k2) * 4 + j) * 64);
          }
        }
#pragma unroll
        for (int k2 = 0; k2 < 4; ++k2) {
          int kt = ktBase + g * 4 + k2;
          union { u64 q[4]; u32 w[8]; } r;
          r.q[0] = raw[g][k2][0]; r.q[1] = raw[g][k2][1];
          r.q[2] = raw[g][k2][2]; r.q[3] = raw[g][k2][3];
          union { f16x8 v; u16 s[8]; } ah, al;
#pragma unroll
          for (int j = 0; j < 8; ++j) {
            ah.s[j] = (u16)(r.w[j] & 0xffffu);
            al.s[j] = (u16)(r.w[j] >> 16);
          }
#pragma unroll
          for (int mat = 0; mat < 2; ++mat)
#pragma unroll
            for (int nn = 0; nn < 2; ++nn) {
              int f = ((mat * 16 + kt) * 2 + nn) * 2;
              f16x8 w1 = *(const f16x8*)(pool + OFF_W + (size_t)f * 1024 + lane * 16);
              f16x8 w2 = *(const f16x8*)(pool + OFF_W + (size_t)(f + 1) * 1024 + lane * 16);
              acc[mat][nn][0] = mfma16(ah.v, w1, acc[mat][nn][0]);
              acc[mat][nn][1] = mfma16(ah.v, w2, acc[mat][nn][1]);
              acc[mat][nn][1] = mfma16(al.v, w1, acc[mat][nn][1]);
            }
        }
      }
      __builtin_amdgcn_s_setprio(0);

      // kh-half reduction through LDS
      if (kh == 1) {
#pragma unroll
        for (int mat = 0; mat < 2; ++mat)
#pragma unroll
          for (int nn = 0; nn < 2; ++nn) {
            f32x4 comb = acc[mat][nn][0] + acc[mat][nn][1] * (1.0f / 2048.0f);
            *(f32x4*)(redf + mh2 * 1024 + ((mat * 2 + nn) * 64 + lane) * 4) = comb;
          }
      }
      __syncthreads();

      if (kh == 0) {
#pragma unroll
        for (int nn = 0; nn < 2; ++nn) {
          f32x4 tot[2];
#pragma unroll
          for (int mat = 0; mat < 2; ++mat) {
            f32x4 oth = *(const f32x4*)(redf + mh2 * 1024 + ((mat * 2 + nn) * 64 + lane) * 4);
            tot[mat] = acc[mat][nn][0] + acc[mat][nn][1] * (1.0f / 2048.0f) + oth;
          }
#pragma unroll
          for (int r4 = 0; r4 < 4; ++r4) {
            int brow = mh2 * 16 + quad * 4 + r4;
            int cc = nn * 16 + l15;
            float pre0 = tot[0][r4] + sbI[cc];
            float pre1 = tot[1][r4] + sbC[cc];
            for (int i = 0; i < KI; ++i) {
              pre0 += sInI[brow * 8 + i] * sWI[i * 32 + cc];
              pre1 += sInC[brow * 8 + i] * sWC[i * 32 + cc];
            }
            if (kap == 8) {
              float fg = sigmoidf_(pre0);
              float og = sigmoidf_(pre1);
              u64 v = (u64)__builtin_bit_cast(u32, fg) |
                      ((u64)__builtin_bit_cast(u32, og) << 32);
              sta64(&g_fo[t & 1][(size_t)brow * H_ + C0A + cc], v);
            } else {
              float lv = sigmoidf_(pre0) * tanhf(pre1);
              f16 hi = (f16)lv;
              f16 lo = (f16)((lv - (float)hi) * 2048.0f);
              u32 pw = (u32)f16bits(hi) | ((u32)f16bits(lo) << 16);
              // LDS stage in fragment order:
              // stage u32 idx = ((mh2*4 + jl)*64 + quadl*16 + quad*4 + r4)*2 + half
              int quadl = cc >> 3, jl = (cc & 7) >> 1, half = cc & 1;
              stg[(((mh2 * 4 + jl) * 64) + quadl * 16 + quad * 4 + r4) * 2 + half] = pw;
            }
          }
        }
      }
      __syncthreads();                 // stage visible; also drains fo stores
      if (kap != 8) {
        // coalesced l store: 1024 u64, 512 thr x 2 — 512B/instr per wave
        const u64* stg64 = (const u64*)(pool + OFF_STG);
        u64* dst = (u64*)g_lp[t & 1];
#pragma unroll
        for (int e = 0; e < 2; ++e) {
          int el = tid + e * 512;
          int m2 = el >> 8, rem = el & 255;
          sta64(dst + ((size_t)(kap * 4 + m2) * 16 + ktA) * 256 + rem, stg64[el]);
        }
      }
      __syncthreads();                 // drains all waves' vmcnt
      if (tid == 0) sta16(&g_lflag[wg], (u16)(t + 1));

    } else {
      // ================= B: u = tanh((l@W_a)*c + b_a), softmax, c/h ======
      // ---- WG gate: 144 u16 l-flags, wave 0 polls 36 lda64, backoff -----
      if (wv == 0) {
        const u32 tgt = (u32)(t + 1);
        int spin = 0;
        for (;;) {
          bool ok = true;
          if (lane < 36) ok = flags4_ge(lda64((const u64*)g_lflag + lane), tgt);
          if (__all(ok)) break;
          if (spin > 2) __builtin_amdgcn_s_sleep(4);
          else          __builtin_amdgcn_s_sleep(1);
          ++spin;
        }
      }
      __syncthreads();

      // fo prefetch (1 u64/thread), consumed in the scalar tail
      u64 foPre = lda64(&g_fo[t & 1][(size_t)(R0B + (tid >> 5)) * H_ + C0B + (tid & 31)]);

      const int chP = wv >> 1, kh = wv & 1;
      const int ktBase = kh * 8;
      const int mh2B = R0B >> 4;
      const u64* lF = (const u64*)g_lp[t & 1];
      const int smxkt = C0B >> 5;      // the kt whose k-range == this col tile

      // per-ch fragment bases (contiguous-512B per lda64)
      const u64* lb[2];
#pragma unroll
      for (int ch = 0; ch < 2; ++ch)
        lb[ch] = lF + ((((size_t)(chP * 2 + ch) * 4 + mh2B) * 16 + ktBase) * 4) * 64 + lane;

      u64 raw[2][4][2][4];             // [buf][kt2][ch][j]
#pragma unroll
      for (int k2 = 0; k2 < 4; ++k2)
#pragma unroll
        for (int ch = 0; ch < 2; ++ch) {
#pragma unroll
          for (int j = 0; j < 4; ++j)
            raw[0][k2][ch][j] = lda64(lb[ch] + (size_t)(k2 * 4 + j) * 64);
        }
      f32x4 acc[2][2][2] = {};   // [ch][nn][hi/lo]
      __builtin_amdgcn_s_setprio(1);
      for (int g = 0; g < 2; ++g) {
        if (g == 0) {
#pragma unroll
          for (int k2 = 0; k2 < 4; ++k2)
#pragma unroll
            for (int ch = 0; ch < 2; ++ch) {
#pragma unroll
              for (int j = 0; j < 4; ++j)
                raw[1][k2][ch][j] = lda64(lb[ch] + (size_t)((4 + k2) * 4 + j) * 64);
            }
        }
#pragma unroll
        for (int k2 = 0; k2 < 4; ++k2) {
          int kt = ktBase + g * 4 + k2;
#pragma unroll
          for (int ch = 0; ch < 2; ++ch) {
            union { u64 q[4]; u32 w[8]; } r;
            r.q[0] = raw[g][k2][ch][0]; r.q[1] = raw[g][k2][ch][1];
            r.q[2] = raw[g][k2][ch][2]; r.q[3] = raw[g][k2][ch][3];
            if (kt == smxkt) {
              // this fragment IS the 16x32 l-tile needed by softmax
              u32* d = (u32*)(pool + OFF_SMX +
                       (((size_t)(chP * 2 + ch) * 16 + l15) * 32 + quad * 8) * 4);
              *(uint4*)d       = make_uint4(r.w[0], r.w[1], r.w[2], r.w[3]);
              *(uint4*)(d + 4) = make_uint4(r.w[4], r.w[5], r.w[6], r.w[7]);
            }
            union { f16x8 v; u16 s[8]; } ah, al;
#pragma unroll
            for (int j = 0; j < 8; ++j) {
              ah.s[j] = (u16)(r.w[j] & 0xffffu);
              al.s[j] = (u16)(r.w[j] >> 16);
            }
#pragma unroll
            for (int nn = 0; nn < 2; ++nn) {
              int f = (kt * 2 + nn) * 2;
              f16x8 w1 = *(const f16x8*)(pool + OFF_W + (size_t)f * 1024 + lane * 16);
              f16x8 w2 = *(const f16x8*)(pool + OFF_W + (size_t)(f + 1) * 1024 + lane * 16);
              acc[ch][nn][0] = mfma16(ah.v, w1, acc[ch][nn][0]);
              acc[ch][nn][1] = mfma16(ah.v, w2, acc[ch][nn][1]);
              acc[ch][nn][1] = mfma16(al.v, w1, acc[ch][nn][1]);
            }
          }
        }
      }
      __builtin_amdgcn_s_setprio(0);

      if (kh == 1) {
#pragma unroll
        for (int ch = 0; ch < 2; ++ch)
#pragma unroll
          for (int nn = 0; nn < 2; ++nn) {
            f32x4 comb = acc[ch][nn][0] + acc[ch][nn][1] * (1.0f / 2048.0f);
            *(f32x4*)(redf + chP * 1024 + ((ch * 2 + nn) * 64 + lane) * 4) = comb;
          }
      }
      __syncthreads();
      if (kh == 0) {
#pragma unroll
        for (int ch = 0; ch < 2; ++ch)
#pragma unroll
          for (int nn = 0; nn < 2; ++nn) {
            f32x4 oth = *(const f32x4*)(redf + chP * 1024 + ((ch * 2 + nn) * 64 + lane) * 4);
            f32x4 dot = acc[ch][nn][0] + acc[ch][nn][1] * (1.0f / 2048.0f) + oth;
#pragma unroll
            for (int r4 = 0; r4 < 4; ++r4) {
              int bl = quad * 4 + r4;
              int cc = nn * 16 + l15;
              float uv = tanhf(dot[r4] * cl_[bl * 32 + cc] + sba[cc]);
              uf[(chP * 2 + ch) * 512 + bl * 32 + cc] = uv;
            }
          }
      }
      __syncthreads();

      // softmax over 8 channels, c/h update, outputs (512 thr, 1 elem each)
      {
        int bl = tid >> 5, cc = tid & 31;
        int bg = R0B + bl, cgl = C0B + cc;
        float uv[8], um = -1e30f;
#pragma unroll
        for (int k = 0; k < 8; ++k) { uv[k] = uf[k * 512 + tid]; um = fmaxf(um, uv[k]); }
        float e[8], s = 0.0f;
#pragma unroll
        for (int k = 0; k < 8; ++k) { e[k] = expf(uv[k] - um); s += e[k]; }
        float inv = 1.0f / s;
        float L = 0.0f;
#pragma unroll
        for (int k = 0; k < 8; ++k) {
          u32 pw = *(const u32*)(pool + OFF_SMX + ((size_t)k * 512 + tid) * 4);
          float lvv = (float)bitsf16((u16)(pw & 0xffffu)) +
                      (float)bitsf16((u16)(pw >> 16)) * (1.0f / 2048.0f);
          L += e[k] * inv * lvv;
        }
        float fg = __builtin_bit_cast(float, (u32)(foPre & 0xffffffffu));
        float og = __builtin_bit_cast(float, (u32)(foPre >> 32));
        float co = cl_[bl * 32 + cc];
        float cn = fg * co + L;
        float hn = og * tanhf(cn);
        cl_[bl * 32 + cc] = cn;
        f16 hh = (f16)hn;
        f16 hl = (f16)((hn - (float)hh) * 2048.0f);
        // LDS stage in fragment order:
        // stage u32 idx = (jl*64 + quadl*16 + bl)*2 + half
        {
          int quadl = cc >> 3, jl = (cc & 7) >> 1, half = cc & 1;
          stg[((jl * 64) + quadl * 16 + bl) * 2 + half] =
              (u32)f16bits(hh) | ((u32)f16bits(hl) << 16);
        }
        p.out[(size_t)B_ * H_ + ((size_t)bg * T_ + t) * H_ + cgl] = hn;
        if (t == T_ - 1) p.out[(size_t)bg * H_ + cgl] = hn;
      }
      __syncthreads();                 // stage visible
      if (tid < 256) {
        // coalesced h store: 256 u64 — 512B/instr per wave
        const u64* stg64 = (const u64*)(pool + OFF_STG);
        sta64((u64*)g_hp[t & 1] + ((size_t)(R0B >> 4) * 16 + (C0B >> 5)) * 256 + tid,
              stg64[tid]);
      }
      __syncthreads();                 // drains all waves' vmcnt
      if (tid == 0) sta16(&g_hflag[wg - NA_WG], (u16)(t + 1));
    }
  }
}

// ---------------------------------------------------------------------------
extern "C" void kernel_launch(void* const* d_in, const int* in_sizes, int n_in,
                              void* d_out, int out_size, void* d_ws, size_t ws_size,
                              hipStream_t stream) {
  (void)in_sizes; (void)n_in; (void)out_size; (void)d_ws; (void)ws_size;

  P p;
  p.Y = (const float*)d_in[0];
  for (int i = 0; i < 7; ++i) p.x[i] = (const float*)d_in[1 + i];
  p.W_i   = (const float*)d_in[8];  p.U_i   = (const float*)d_in[9];  p.b_i   = (const float*)d_in[10];
  p.W_f   = (const float*)d_in[11]; p.U_f   = (const float*)d_in[12]; p.b_f   = (const float*)d_in[13];
  p.W_c   = (const float*)d_in[14]; p.U_c   = (const float*)d_in[15]; p.b_c   = (const float*)d_in[16];
  p.W_o   = (const float*)d_in[17]; p.U_o   = (const float*)d_in[18]; p.b_o   = (const float*)d_in[19];
  p.W_i_x = (const float*)d_in[20]; p.U_i_x = (const float*)d_in[21]; p.b_i_x = (const float*)d_in[22];
  p.W_c_x = (const float*)d_in[23]; p.U_c_x = (const float*)d_in[24]; p.b_c_x = (const float*)d_in[25];
  p.W_a   = (const float*)d_in[26]; p.b_a   = (const float*)d_in[27];
  p.out   = (float*)d_out;

  prep_kernel<<<dim3(256), dim3(256), 0, stream>>>(p);

  void* kargs[] = { (void*)&p };
  hipError_t err = hipLaunchCooperativeKernel((void*)lstm_main, dim3(NWG), dim3(NTHR),
                                              kargs, 0, stream);
  if (err != hipSuccess) {
    // Fallback: plain launch. 208 blocks, 1/CU (LDS-bound) => co-resident on
    // 256 CUs; the flag protocol only needs co-residency, not coop launch.
    lstm_main<<<dim3(NWG), dim3(NTHR), 0, stream>>>(p);
  }
}